// Round 2
// baseline (13692.557 us; speedup 1.0000x reference)
//
#include <hip/hip_runtime.h>
#include <hip/hip_bf16.h>
#include <math.h>

#define BB 8
#define NN 2048
#define KK 10
#define BN (BB * NN)

#define TR 64
#define TC 64
#define TF 32

// ---------------------------------------------------------------------------
// sq[i] = sum_f x[i,f]^2
__global__ void sqnorm_kernel(const float* __restrict__ x, float* __restrict__ sq, int F) {
    int i = blockIdx.x * blockDim.x + threadIdx.x;
    if (i >= BN) return;
    const float* xp = x + (size_t)i * F;
    float s = 0.f;
    for (int f = 0; f < F; ++f) { float v = xp[f]; s += v * v; }
    sq[i] = s;
}

// ---------------------------------------------------------------------------
// Per (batch, 64-row tile): compute d2 against all N cols via tiled GEMM,
// maintain top-K smallest (tie -> lowest index, matching jax.lax.top_k).
__global__ __launch_bounds__(256) void knn_kernel(const float* __restrict__ x,
                                                  const float* __restrict__ sq,
                                                  int* __restrict__ idx, int F) {
    int b = blockIdx.y;
    int row0 = blockIdx.x * TR;
    const float* xb = x + (size_t)b * NN * F;
    const float* sqb = sq + (size_t)b * NN;

    __shared__ float As[TR][TF];
    __shared__ float Bs[TC][TF];
    __shared__ float Ds[TR][TC + 1];

    int tid = threadIdx.x;
    int tr = (tid / 16) * 4;
    int tc = (tid % 16) * 4;

    float bestd[KK];
    int bestidx[KK];
#pragma unroll
    for (int k = 0; k < KK; ++k) { bestd[k] = INFINITY; bestidx[k] = 0; }

    for (int col0 = 0; col0 < NN; col0 += TC) {
        float acc[4][4];
#pragma unroll
        for (int i = 0; i < 4; ++i)
#pragma unroll
            for (int j = 0; j < 4; ++j) acc[i][j] = 0.f;

        for (int f0 = 0; f0 < F; f0 += TF) {
            __syncthreads();
            for (int l = tid; l < TR * TF; l += 256) {
                int r = l / TF, f = l % TF;
                As[r][f] = (f0 + f < F) ? xb[(size_t)(row0 + r) * F + f0 + f] : 0.f;
            }
            for (int l = tid; l < TC * TF; l += 256) {
                int c = l / TF, f = l % TF;
                Bs[c][f] = (f0 + f < F) ? xb[(size_t)(col0 + c) * F + f0 + f] : 0.f;
            }
            __syncthreads();
#pragma unroll
            for (int f = 0; f < TF; ++f) {
                float a[4], bv[4];
#pragma unroll
                for (int i = 0; i < 4; ++i) a[i] = As[tr + i][f];
#pragma unroll
                for (int j = 0; j < 4; ++j) bv[j] = Bs[tc + j][f];
#pragma unroll
                for (int i = 0; i < 4; ++i)
#pragma unroll
                    for (int j = 0; j < 4; ++j) acc[i][j] += a[i] * bv[j];
            }
        }
        __syncthreads();
#pragma unroll
        for (int i = 0; i < 4; ++i)
#pragma unroll
            for (int j = 0; j < 4; ++j) {
                int r = tr + i, c = tc + j;
                Ds[r][c] = (sqb[row0 + r] + sqb[col0 + c]) - 2.f * acc[i][j];
            }
        __syncthreads();
        if (tid < TR) {
            for (int c = 0; c < TC; ++c) {
                float d = Ds[tid][c];
                if (d < bestd[KK - 1]) {   // strict: equal keeps earlier (lower) index
                    bestd[KK - 1] = d;
                    bestidx[KK - 1] = col0 + c;
#pragma unroll
                    for (int p = KK - 1; p > 0; --p) {
                        if (bestd[p] < bestd[p - 1]) {   // strict: stable for ties
                            float td = bestd[p]; bestd[p] = bestd[p - 1]; bestd[p - 1] = td;
                            int ti = bestidx[p]; bestidx[p] = bestidx[p - 1]; bestidx[p - 1] = ti;
                        }
                    }
                }
            }
        }
        __syncthreads();
    }
    if (tid < TR) {
        int* op = idx + ((size_t)b * NN + row0 + tid) * KK;
#pragma unroll
        for (int k = 0; k < KK; ++k) op[k] = bestidx[k];
    }
}

// ---------------------------------------------------------------------------
// A = x @ (W1 - W2) + bias ; T = x @ W2.   x:(M,fin)  w:(2*fin,fout)
__global__ __launch_bounds__(256) void gemm2_kernel(const float* __restrict__ x,
                                                    const float* __restrict__ w,
                                                    const float* __restrict__ bias,
                                                    float* __restrict__ Aout,
                                                    float* __restrict__ Tout,
                                                    int fin, int fout) {
    int m0 = blockIdx.x * 64;
    int o0 = blockIdx.y * 64;
    __shared__ float Xs[64][TF + 1];
    __shared__ float W1s[TF][64];
    __shared__ float W2s[TF][64];
    int tid = threadIdx.x;
    int tr = (tid / 16) * 4, tc = (tid % 16) * 4;
    float accA[4][4], accT[4][4];
#pragma unroll
    for (int i = 0; i < 4; ++i)
#pragma unroll
        for (int j = 0; j < 4; ++j) { accA[i][j] = 0.f; accT[i][j] = 0.f; }

    for (int f0 = 0; f0 < fin; f0 += TF) {
        __syncthreads();
        for (int l = tid; l < 64 * TF; l += 256) {
            int r = l / TF, f = l % TF;
            Xs[r][f] = (f0 + f < fin) ? x[(size_t)(m0 + r) * fin + f0 + f] : 0.f;
        }
        for (int l = tid; l < TF * 64; l += 256) {
            int f = l / 64, o = l % 64;
            bool ok = (f0 + f < fin);
            W1s[f][o] = ok ? w[(size_t)(f0 + f) * fout + o0 + o] : 0.f;
            W2s[f][o] = ok ? w[(size_t)(f0 + f + fin) * fout + o0 + o] : 0.f;
        }
        __syncthreads();
#pragma unroll
        for (int f = 0; f < TF; ++f) {
            float a[4], w1[4], w2[4];
#pragma unroll
            for (int i = 0; i < 4; ++i) a[i] = Xs[tr + i][f];
#pragma unroll
            for (int j = 0; j < 4; ++j) { w1[j] = W1s[f][tc + j]; w2[j] = W2s[f][tc + j]; }
#pragma unroll
            for (int i = 0; i < 4; ++i)
#pragma unroll
                for (int j = 0; j < 4; ++j) {
                    accA[i][j] += a[i] * (w1[j] - w2[j]);
                    accT[i][j] += a[i] * w2[j];
                }
        }
    }
#pragma unroll
    for (int i = 0; i < 4; ++i)
#pragma unroll
        for (int j = 0; j < 4; ++j) {
            int m = m0 + tr + i, o = o0 + tc + j;
            Aout[(size_t)m * fout + o] = accA[i][j] + bias[o];
            Tout[(size_t)m * fout + o] = accT[i][j];
        }
}

// ---------------------------------------------------------------------------
// out[n,o] = lrelu(A[n,o] + max_k T[idx[n,k], o])
__global__ void gathermax_kernel(const float* __restrict__ A, const float* __restrict__ T,
                                 const int* __restrict__ idx, float* __restrict__ out,
                                 int fout) {
    int pn = blockIdx.x;                  // 0..BN-1
    int b = pn / NN;
    int o = blockIdx.y * 64 + threadIdx.x;
    const int* ip = idx + (size_t)pn * KK;
    const float* Tb = T + (size_t)b * NN * fout;
    float m = -INFINITY;
#pragma unroll
    for (int k = 0; k < KK; ++k) {
        int j = ip[k];
        m = fmaxf(m, Tb[(size_t)j * fout + o]);
    }
    float h = A[(size_t)pn * fout + o] + m;
    out[(size_t)pn * fout + o] = h > 0.f ? h : 0.2f * h;
}

// ---------------------------------------------------------------------------
// g[b,o] = max_n h[b,n,o]   (fout = 1024)
__global__ void gmax_kernel(const float* __restrict__ h, float* __restrict__ g) {
    int b = blockIdx.y;
    int o = blockIdx.x * 256 + threadIdx.x;
    const float* hp = h + (size_t)b * NN * 1024 + o;
    float m = -INFINITY;
    for (int n = 0; n < NN; ++n) m = fmaxf(m, hp[(size_t)n * 1024]);
    g[(size_t)b * 1024 + o] = m;
}

// ---------------------------------------------------------------------------
// out[b] = ((g @ m0w + m0b) @ m1w + m1b) @ m2w + m2b
__global__ __launch_bounds__(128) void mlp_kernel(const float* __restrict__ g,
                                                  const float* __restrict__ m0w, const float* __restrict__ m0b,
                                                  const float* __restrict__ m1w, const float* __restrict__ m1b,
                                                  const float* __restrict__ m2w, const float* __restrict__ m2b,
                                                  float* __restrict__ out) {
    __shared__ float gs[1024];
    __shared__ float h1[128];
    __shared__ float h2[64];
    int b = blockIdx.x, t = threadIdx.x;
    for (int i = t; i < 1024; i += 128) gs[i] = g[(size_t)b * 1024 + i];
    __syncthreads();
    float s = m0b[t];
    for (int f = 0; f < 1024; ++f) s += gs[f] * m0w[(size_t)f * 128 + t];
    h1[t] = s;
    __syncthreads();
    if (t < 64) {
        float s2 = m1b[t];
        for (int f = 0; f < 128; ++f) s2 += h1[f] * m1w[(size_t)f * 64 + t];
        h2[t] = s2;
    }
    __syncthreads();
    if (t == 0) {
        float s3 = m2b[0];
        for (int f = 0; f < 64; ++f) s3 += h2[f] * m2w[f];
        out[b] = s3;
    }
}

// ---------------------------------------------------------------------------
extern "C" void kernel_launch(void* const* d_in, const int* in_sizes, int n_in,
                              void* d_out, int out_size, void* d_ws, size_t ws_size,
                              hipStream_t stream) {
    const float* x0 = (const float*)d_in[0];
    const float* w[5], * bi[5];
    for (int i = 0; i < 5; ++i) { w[i] = (const float*)d_in[1 + 2 * i]; bi[i] = (const float*)d_in[2 + 2 * i]; }
    const float* m0w = (const float*)d_in[11]; const float* m0b = (const float*)d_in[12];
    const float* m1w = (const float*)d_in[13]; const float* m1b = (const float*)d_in[14];
    const float* m2w = (const float*)d_in[15]; const float* m2b = (const float*)d_in[16];

    float* X0 = (float*)d_ws;
    float* X1 = X0 + (size_t)BN * 1024;
    float* T  = X1 + (size_t)BN * 1024;
    float* SQ = T  + (size_t)BN * 1024;
    int*   IDX = (int*)(SQ + BN);
    float* G  = (float*)(IDX + (size_t)BN * KK);

    const int fouts[5] = {64, 128, 256, 512, 1024};
    const float* cur = x0;
    int fin = 3;
    float* bufs[2] = {X0, X1};

    for (int l = 0; l < 5; ++l) {
        int fout = fouts[l];
        float* nxt = bufs[l & 1];

        sqnorm_kernel<<<(BN + 255) / 256, 256, 0, stream>>>(cur, SQ, fin);

        dim3 kg(NN / TR, BB);
        knn_kernel<<<kg, 256, 0, stream>>>(cur, SQ, IDX, fin);

        dim3 gg(BN / 64, fout / 64);
        gemm2_kernel<<<gg, 256, 0, stream>>>(cur, w[l], bi[l], nxt, T, fin, fout);

        dim3 mg(BN, fout / 64);
        gathermax_kernel<<<mg, 64, 0, stream>>>(nxt, T, IDX, nxt, fout);

        cur = nxt;
        fin = fout;
    }

    dim3 xg(1024 / 256, BB);
    gmax_kernel<<<xg, 256, 0, stream>>>(cur, G);

    mlp_kernel<<<BB, 128, 0, stream>>>(G, m0w, m0b, m1w, m1b, m2w, m2b, (float*)d_out);
}

// Round 3
// 3994.884 us; speedup vs baseline: 3.4275x; 3.4275x over previous
//
#include <hip/hip_runtime.h>
#include <hip/hip_bf16.h>
#include <math.h>

#define BB 8
#define NN 2048
#define KK 10
#define BN (BB * NN)

#define TR 64
#define TC 64
#define TF 32
#define SPLIT 4
#define CPS (NN / SPLIT)   // 512 cols per split-block

// ---------------------------------------------------------------------------
// sq[i] = sum_f x[i,f]^2
__global__ void sqnorm_kernel(const float* __restrict__ x, float* __restrict__ sq, int F) {
    int i = blockIdx.x * blockDim.x + threadIdx.x;
    if (i >= BN) return;
    const float* xp = x + (size_t)i * F;
    float s = 0.f;
    for (int f = 0; f < F; ++f) { float v = xp[f]; s += v * v; }
    sq[i] = s;
}

// ---------------------------------------------------------------------------
// kNN part 1: per (row-tile 64, col-split 512, batch) block.
// GEMM with conflict-free transposed LDS tiles; selection parallelized:
// thread = (row = tid&63, col-quarter = tid>>6), private top-10 in regs,
// then stable 4-way in-block merge -> candD/candI[b][n][split][10].
__global__ __launch_bounds__(256, 4) void knn_part_kernel(const float* __restrict__ x,
                                                          const float* __restrict__ sq,
                                                          float* __restrict__ candD,
                                                          int* __restrict__ candI, int F) {
    int b = blockIdx.z;
    int row0 = blockIdx.x * TR;
    int colbase = blockIdx.y * CPS;
    const float* xb = x + (size_t)b * NN * F;
    const float* sqb = sq + (size_t)b * NN;

    // union-style shared pool: GEMM phase uses As/Bs/Ds; merge phase reuses front.
    __shared__ float smem[TF * 68 * 2 + TR * 65];   // 2*2176 + 4160 = 8512 floats
    float* As = smem;                // [TF][68]
    float* Bs = smem + TF * 68;      // [TF][68]
    float* Ds = smem + TF * 68 * 2;  // [TR][65]

    int tid = threadIdx.x;
    int tr = (tid / 16) * 4;
    int tc = (tid % 16) * 4;
    int srow = tid & 63;
    int squart = tid >> 6;
    int scol0 = squart * 16;

    float bestd[KK];
    int bestidx[KK];
#pragma unroll
    for (int k = 0; k < KK; ++k) { bestd[k] = INFINITY; bestidx[k] = 0x7fffffff; }

    float sqr_r = sqb[row0 + srow];  // only used via Ds below; keep per-GEMM-thread too

    for (int ct = 0; ct < CPS; ct += TC) {
        int col0 = colbase + ct;
        float acc[4][4];
#pragma unroll
        for (int i = 0; i < 4; ++i)
#pragma unroll
            for (int j = 0; j < 4; ++j) acc[i][j] = 0.f;

        for (int f0 = 0; f0 < F; f0 += TF) {
            __syncthreads();
            for (int l = tid; l < TR * TF; l += 256) {
                int r = l / TF, f = l % TF;
                As[f * 68 + r] = (f0 + f < F) ? xb[(size_t)(row0 + r) * F + f0 + f] : 0.f;
                Bs[f * 68 + r] = (f0 + f < F) ? xb[(size_t)(col0 + r) * F + f0 + f] : 0.f;
            }
            __syncthreads();
#pragma unroll
            for (int f = 0; f < TF; ++f) {
                float a[4], bv[4];
#pragma unroll
                for (int i = 0; i < 4; ++i) a[i] = As[f * 68 + tr + i];
#pragma unroll
                for (int j = 0; j < 4; ++j) bv[j] = Bs[f * 68 + tc + j];
#pragma unroll
                for (int i = 0; i < 4; ++i)
#pragma unroll
                    for (int j = 0; j < 4; ++j) acc[i][j] += a[i] * bv[j];
            }
        }
        __syncthreads();
#pragma unroll
        for (int i = 0; i < 4; ++i) {
            float sr = sqb[row0 + tr + i];
#pragma unroll
            for (int j = 0; j < 4; ++j) {
                Ds[(tr + i) * 65 + tc + j] = (sr + sqb[col0 + tc + j]) - 2.f * acc[i][j];
            }
        }
        __syncthreads();
        // selection: each thread scans 16 cols of its row (ascending idx order)
#pragma unroll
        for (int cc = 0; cc < 16; ++cc) {
            int c = scol0 + cc;
            float d = Ds[srow * 65 + c];
            if (d < bestd[KK - 1]) {   // strict: equal keeps earlier (lower) index
                bestd[KK - 1] = d;
                bestidx[KK - 1] = col0 + c;
#pragma unroll
                for (int p = KK - 1; p > 0; --p) {
                    if (bestd[p] < bestd[p - 1]) {
                        float td = bestd[p]; bestd[p] = bestd[p - 1]; bestd[p - 1] = td;
                        int ti = bestidx[p]; bestidx[p] = bestidx[p - 1]; bestidx[p - 1] = ti;
                    }
                }
            }
        }
    }
    __syncthreads();   // all Ds reads done; safe to overlay cand arrays
    float* candd_s = smem;                       // [256][KK]
    int* candi_s = (int*)(smem + 256 * KK);      // [256][KK]
#pragma unroll
    for (int k = 0; k < KK; ++k) {
        candd_s[tid * KK + k] = bestd[k];
        candi_s[tid * KK + k] = bestidx[k];
    }
    __syncthreads();
    if (tid < TR) {
        int p[4] = {0, 0, 0, 0};
        size_t base = ((size_t)((size_t)b * NN + row0 + tid) * SPLIT + blockIdx.y) * KK;
        for (int s = 0; s < KK; ++s) {
            float bD = INFINITY; int bI = 0x7fffffff; int bq = 0;
#pragma unroll
            for (int q = 0; q < 4; ++q) {
                if (p[q] < KK) {
                    int li = (q * 64 + tid) * KK + p[q];
                    float d = candd_s[li]; int ii = candi_s[li];
                    if (d < bD || (d == bD && ii < bI)) { bD = d; bI = ii; bq = q; }
                }
            }
            p[bq]++;
            candD[base + s] = bD;
            candI[base + s] = bI;
        }
    }
}

// ---------------------------------------------------------------------------
// kNN part 2: per row, merge SPLIT sorted 10-lists -> final top-10 indices.
__global__ void knn_merge_kernel(const float* __restrict__ candD,
                                 const int* __restrict__ candI,
                                 int* __restrict__ idx) {
    int g = blockIdx.x * blockDim.x + threadIdx.x;
    if (g >= BN) return;
    size_t base = (size_t)g * SPLIT * KK;
    int p[SPLIT];
#pragma unroll
    for (int q = 0; q < SPLIT; ++q) p[q] = 0;
    int* op = idx + (size_t)g * KK;
    for (int s = 0; s < KK; ++s) {
        float bD = INFINITY; int bI = 0x7fffffff; int bq = 0;
#pragma unroll
        for (int q = 0; q < SPLIT; ++q) {
            if (p[q] < KK) {
                float d = candD[base + q * KK + p[q]];
                int ii = candI[base + q * KK + p[q]];
                if (d < bD || (d == bD && ii < bI)) { bD = d; bI = ii; bq = q; }
            }
        }
        p[bq]++;
        op[s] = bI;
    }
}

// ---------------------------------------------------------------------------
// A = x @ (W1 - W2) + bias ; T = x @ W2.   x:(M,fin)  w:(2*fin,fout)
__global__ __launch_bounds__(256) void gemm2_kernel(const float* __restrict__ x,
                                                    const float* __restrict__ w,
                                                    const float* __restrict__ bias,
                                                    float* __restrict__ Aout,
                                                    float* __restrict__ Tout,
                                                    int fin, int fout) {
    int m0 = blockIdx.x * 64;
    int o0 = blockIdx.y * 64;
    __shared__ float Xs[64][TF + 1];
    __shared__ float W1s[TF][64];
    __shared__ float W2s[TF][64];
    int tid = threadIdx.x;
    int tr = (tid / 16) * 4, tc = (tid % 16) * 4;
    float accA[4][4], accT[4][4];
#pragma unroll
    for (int i = 0; i < 4; ++i)
#pragma unroll
        for (int j = 0; j < 4; ++j) { accA[i][j] = 0.f; accT[i][j] = 0.f; }

    for (int f0 = 0; f0 < fin; f0 += TF) {
        __syncthreads();
        for (int l = tid; l < 64 * TF; l += 256) {
            int r = l / TF, f = l % TF;
            Xs[r][f] = (f0 + f < fin) ? x[(size_t)(m0 + r) * fin + f0 + f] : 0.f;
        }
        for (int l = tid; l < TF * 64; l += 256) {
            int f = l / 64, o = l % 64;
            bool ok = (f0 + f < fin);
            W1s[f][o] = ok ? w[(size_t)(f0 + f) * fout + o0 + o] : 0.f;
            W2s[f][o] = ok ? w[(size_t)(f0 + f + fin) * fout + o0 + o] : 0.f;
        }
        __syncthreads();
#pragma unroll
        for (int f = 0; f < TF; ++f) {
            float a[4], w1[4], w2[4];
#pragma unroll
            for (int i = 0; i < 4; ++i) a[i] = Xs[tr + i][f];
#pragma unroll
            for (int j = 0; j < 4; ++j) { w1[j] = W1s[f][tc + j]; w2[j] = W2s[f][tc + j]; }
#pragma unroll
            for (int i = 0; i < 4; ++i)
#pragma unroll
                for (int j = 0; j < 4; ++j) {
                    accA[i][j] += a[i] * (w1[j] - w2[j]);
                    accT[i][j] += a[i] * w2[j];
                }
        }
    }
#pragma unroll
    for (int i = 0; i < 4; ++i)
#pragma unroll
        for (int j = 0; j < 4; ++j) {
            int m = m0 + tr + i, o = o0 + tc + j;
            Aout[(size_t)m * fout + o] = accA[i][j] + bias[o];
            Tout[(size_t)m * fout + o] = accT[i][j];
        }
}

// ---------------------------------------------------------------------------
// out[n,o] = lrelu(A[n,o] + max_k T[idx[n,k], o])
__global__ void gathermax_kernel(const float* __restrict__ A, const float* __restrict__ T,
                                 const int* __restrict__ idx, float* __restrict__ out,
                                 int fout) {
    int pn = blockIdx.x;                  // 0..BN-1
    int b = pn / NN;
    int o = blockIdx.y * 64 + threadIdx.x;
    const int* ip = idx + (size_t)pn * KK;
    const float* Tb = T + (size_t)b * NN * fout;
    float m = -INFINITY;
#pragma unroll
    for (int k = 0; k < KK; ++k) {
        int j = ip[k];
        m = fmaxf(m, Tb[(size_t)j * fout + o]);
    }
    float h = A[(size_t)pn * fout + o] + m;
    out[(size_t)pn * fout + o] = h > 0.f ? h : 0.2f * h;
}

// ---------------------------------------------------------------------------
// g[b,o] = max_n h[b,n,o]   (fout = 1024)
__global__ void gmax_kernel(const float* __restrict__ h, float* __restrict__ g) {
    int b = blockIdx.y;
    int o = blockIdx.x * 256 + threadIdx.x;
    const float* hp = h + (size_t)b * NN * 1024 + o;
    float m = -INFINITY;
    for (int n = 0; n < NN; ++n) m = fmaxf(m, hp[(size_t)n * 1024]);
    g[(size_t)b * 1024 + o] = m;
}

// ---------------------------------------------------------------------------
// out[b] = ((g @ m0w + m0b) @ m1w + m1b) @ m2w + m2b
__global__ __launch_bounds__(128) void mlp_kernel(const float* __restrict__ g,
                                                  const float* __restrict__ m0w, const float* __restrict__ m0b,
                                                  const float* __restrict__ m1w, const float* __restrict__ m1b,
                                                  const float* __restrict__ m2w, const float* __restrict__ m2b,
                                                  float* __restrict__ out) {
    __shared__ float gs[1024];
    __shared__ float h1[128];
    __shared__ float h2[64];
    int b = blockIdx.x, t = threadIdx.x;
    for (int i = t; i < 1024; i += 128) gs[i] = g[(size_t)b * 1024 + i];
    __syncthreads();
    float s = m0b[t];
    for (int f = 0; f < 1024; ++f) s += gs[f] * m0w[(size_t)f * 128 + t];
    h1[t] = s;
    __syncthreads();
    if (t < 64) {
        float s2 = m1b[t];
        for (int f = 0; f < 128; ++f) s2 += h1[f] * m1w[(size_t)f * 64 + t];
        h2[t] = s2;
    }
    __syncthreads();
    if (t == 0) {
        float s3 = m2b[0];
        for (int f = 0; f < 64; ++f) s3 += h2[f] * m2w[f];
        out[b] = s3;
    }
}

// ---------------------------------------------------------------------------
extern "C" void kernel_launch(void* const* d_in, const int* in_sizes, int n_in,
                              void* d_out, int out_size, void* d_ws, size_t ws_size,
                              hipStream_t stream) {
    const float* x0 = (const float*)d_in[0];
    const float* w[5], * bi[5];
    for (int i = 0; i < 5; ++i) { w[i] = (const float*)d_in[1 + 2 * i]; bi[i] = (const float*)d_in[2 + 2 * i]; }
    const float* m0w = (const float*)d_in[11]; const float* m0b = (const float*)d_in[12];
    const float* m1w = (const float*)d_in[13]; const float* m1b = (const float*)d_in[14];
    const float* m2w = (const float*)d_in[15]; const float* m2b = (const float*)d_in[16];

    float* X0 = (float*)d_ws;
    float* X1 = X0 + (size_t)BN * 1024;
    float* T  = X1 + (size_t)BN * 1024;
    float* SQ = T  + (size_t)BN * 1024;
    int*   IDX = (int*)(SQ + BN);
    float* G  = (float*)(IDX + (size_t)BN * KK);

    // candidate buffers overlaid on T region (T written only after kNN done)
    float* candD = T;
    int*   candI = (int*)(T + (size_t)BN * SPLIT * KK);

    const int fouts[5] = {64, 128, 256, 512, 1024};
    const float* cur = x0;
    int fin = 3;
    float* bufs[2] = {X0, X1};

    for (int l = 0; l < 5; ++l) {
        int fout = fouts[l];
        float* nxt = bufs[l & 1];

        sqnorm_kernel<<<(BN + 255) / 256, 256, 0, stream>>>(cur, SQ, fin);

        dim3 kg(NN / TR, SPLIT, BB);
        knn_part_kernel<<<kg, 256, 0, stream>>>(cur, SQ, candD, candI, fin);
        knn_merge_kernel<<<(BN + 255) / 256, 256, 0, stream>>>(candD, candI, IDX);

        dim3 gg(BN / 64, fout / 64);
        gemm2_kernel<<<gg, 256, 0, stream>>>(cur, w[l], bi[l], nxt, T, fin, fout);

        dim3 mg(BN, fout / 64);
        gathermax_kernel<<<mg, 64, 0, stream>>>(nxt, T, IDX, nxt, fout);

        cur = nxt;
        fin = fout;
    }

    dim3 xg(1024 / 256, BB);
    gmax_kernel<<<xg, 256, 0, stream>>>(cur, G);

    mlp_kernel<<<BB, 128, 0, stream>>>(G, m0w, m0b, m1w, m1b, m2w, m2b, (float*)d_out);
}

// Round 5
// 3069.862 us; speedup vs baseline: 4.4603x; 1.3013x over previous
//
#include <hip/hip_runtime.h>
#include <hip/hip_bf16.h>
#include <math.h>

#define BB 8
#define NN 2048
#define KK 10
#define BN (BB * NN)

#define TR 64
#define TC 64
#define TF 32
#define SPLIT 4
#define CPS (NN / SPLIT)   // 512 cols per split-block

typedef __attribute__((ext_vector_type(8))) short bf16x8;
typedef __attribute__((ext_vector_type(4))) float f32x4;

__device__ inline unsigned short f2bf(float f) {
    unsigned int u = __float_as_uint(f);
    unsigned int r = u + 0x7fffu + ((u >> 16) & 1u);
    return (unsigned short)(r >> 16);
}
__device__ inline float bf2f(unsigned short h) {
    return __uint_as_float((unsigned int)h << 16);
}

// ---------------------------------------------------------------------------
// sq[i] = sum_f x[i,f]^2
__global__ void sqnorm_kernel(const float* __restrict__ x, float* __restrict__ sq, int F) {
    int i = blockIdx.x * blockDim.x + threadIdx.x;
    if (i >= BN) return;
    const float* xp = x + (size_t)i * F;
    float s = 0.f;
    for (int f = 0; f < F; ++f) { float v = xp[f]; s += v * v; }
    sq[i] = s;
}

// ---------------------------------------------------------------------------
// kNN part 1 (unchanged from round 3 — validated)
__global__ __launch_bounds__(256, 4) void knn_part_kernel(const float* __restrict__ x,
                                                          const float* __restrict__ sq,
                                                          float* __restrict__ candD,
                                                          int* __restrict__ candI, int F) {
    int b = blockIdx.z;
    int row0 = blockIdx.x * TR;
    int colbase = blockIdx.y * CPS;
    const float* xb = x + (size_t)b * NN * F;
    const float* sqb = sq + (size_t)b * NN;

    __shared__ float smem[TF * 68 * 2 + TR * 65];
    float* As = smem;
    float* Bs = smem + TF * 68;
    float* Ds = smem + TF * 68 * 2;

    int tid = threadIdx.x;
    int tr = (tid / 16) * 4;
    int tc = (tid % 16) * 4;
    int srow = tid & 63;
    int squart = tid >> 6;
    int scol0 = squart * 16;

    float bestd[KK];
    int bestidx[KK];
#pragma unroll
    for (int k = 0; k < KK; ++k) { bestd[k] = INFINITY; bestidx[k] = 0x7fffffff; }

    for (int ct = 0; ct < CPS; ct += TC) {
        int col0 = colbase + ct;
        float acc[4][4];
#pragma unroll
        for (int i = 0; i < 4; ++i)
#pragma unroll
            for (int j = 0; j < 4; ++j) acc[i][j] = 0.f;

        for (int f0 = 0; f0 < F; f0 += TF) {
            __syncthreads();
            for (int l = tid; l < TR * TF; l += 256) {
                int r = l / TF, f = l % TF;
                As[f * 68 + r] = (f0 + f < F) ? xb[(size_t)(row0 + r) * F + f0 + f] : 0.f;
                Bs[f * 68 + r] = (f0 + f < F) ? xb[(size_t)(col0 + r) * F + f0 + f] : 0.f;
            }
            __syncthreads();
#pragma unroll
            for (int f = 0; f < TF; ++f) {
                float a[4], bv[4];
#pragma unroll
                for (int i = 0; i < 4; ++i) a[i] = As[f * 68 + tr + i];
#pragma unroll
                for (int j = 0; j < 4; ++j) bv[j] = Bs[f * 68 + tc + j];
#pragma unroll
                for (int i = 0; i < 4; ++i)
#pragma unroll
                    for (int j = 0; j < 4; ++j) acc[i][j] += a[i] * bv[j];
            }
        }
        __syncthreads();
#pragma unroll
        for (int i = 0; i < 4; ++i) {
            float sr = sqb[row0 + tr + i];
#pragma unroll
            for (int j = 0; j < 4; ++j) {
                Ds[(tr + i) * 65 + tc + j] = (sr + sqb[col0 + tc + j]) - 2.f * acc[i][j];
            }
        }
        __syncthreads();
#pragma unroll
        for (int cc = 0; cc < 16; ++cc) {
            int c = scol0 + cc;
            float d = Ds[srow * 65 + c];
            if (d < bestd[KK - 1]) {
                bestd[KK - 1] = d;
                bestidx[KK - 1] = col0 + c;
#pragma unroll
                for (int p = KK - 1; p > 0; --p) {
                    if (bestd[p] < bestd[p - 1]) {
                        float td = bestd[p]; bestd[p] = bestd[p - 1]; bestd[p - 1] = td;
                        int ti = bestidx[p]; bestidx[p] = bestidx[p - 1]; bestidx[p - 1] = ti;
                    }
                }
            }
        }
    }
    __syncthreads();
    float* candd_s = smem;
    int* candi_s = (int*)(smem + 256 * KK);
#pragma unroll
    for (int k = 0; k < KK; ++k) {
        candd_s[tid * KK + k] = bestd[k];
        candi_s[tid * KK + k] = bestidx[k];
    }
    __syncthreads();
    if (tid < TR) {
        int p[4] = {0, 0, 0, 0};
        size_t base = ((size_t)((size_t)b * NN + row0 + tid) * SPLIT + blockIdx.y) * KK;
        for (int s = 0; s < KK; ++s) {
            float bD = INFINITY; int bI = 0x7fffffff; int bq = 0;
#pragma unroll
            for (int q = 0; q < 4; ++q) {
                if (p[q] < KK) {
                    int li = (q * 64 + tid) * KK + p[q];
                    float d = candd_s[li]; int ii = candi_s[li];
                    if (d < bD || (d == bD && ii < bI)) { bD = d; bI = ii; bq = q; }
                }
            }
            p[bq]++;
            candD[base + s] = bD;
            candI[base + s] = bI;
        }
    }
}

// ---------------------------------------------------------------------------
__global__ void knn_merge_kernel(const float* __restrict__ candD,
                                 const int* __restrict__ candI,
                                 int* __restrict__ idx) {
    int g = blockIdx.x * blockDim.x + threadIdx.x;
    if (g >= BN) return;
    size_t base = (size_t)g * SPLIT * KK;
    int p[SPLIT];
#pragma unroll
    for (int q = 0; q < SPLIT; ++q) p[q] = 0;
    int* op = idx + (size_t)g * KK;
    for (int s = 0; s < KK; ++s) {
        float bD = INFINITY; int bI = 0x7fffffff; int bq = 0;
#pragma unroll
        for (int q = 0; q < SPLIT; ++q) {
            if (p[q] < KK) {
                float d = candD[base + q * KK + p[q]];
                int ii = candI[base + q * KK + p[q]];
                if (d < bD || (d == bD && ii < bI)) { bD = d; bI = ii; bq = q; }
            }
        }
        p[bq]++;
        op[s] = bI;
    }
}

// ---------------------------------------------------------------------------
// split x (fp32) into hi/lo bf16
__global__ void xsplit_kernel(const float* __restrict__ x, unsigned short* __restrict__ hi,
                              unsigned short* __restrict__ lo, int n) {
    int i = blockIdx.x * blockDim.x + threadIdx.x;
    if (i >= n) return;
    float v = x[i];
    unsigned short h = f2bf(v);
    hi[i] = h;
    lo[i] = f2bf(v - bf2f(h));
}

// ---------------------------------------------------------------------------
// Build WT[o'][2*fin] bf16: rows o'<fout -> (W1-W2) col o', else W2 col o'-fout.
// k-dim: [0,fin) = hi, [fin,2fin) = lo.  w is (2*fin, fout) row-major.
__global__ void wsplit_kernel(const float* __restrict__ w, unsigned short* __restrict__ WT,
                              int fin, int fout) {
    int i = blockIdx.x * blockDim.x + threadIdx.x;
    int total = 2 * fout * fin;
    if (i >= total) return;
    int op = i % (2 * fout);
    int f = i / (2 * fout);
    float v;
    if (op < fout) v = w[(size_t)f * fout + op] - w[(size_t)(fin + f) * fout + op];
    else v = w[(size_t)(fin + f) * fout + (op - fout)];
    unsigned short h = f2bf(v);
    unsigned short l = f2bf(v - bf2f(h));
    WT[(size_t)op * (2 * fin) + f] = h;
    WT[(size_t)op * (2 * fin) + fin + f] = l;
}

// ---------------------------------------------------------------------------
// MFMA GEMM: out[M][2*fout] = xsplit @ WT^T (3-phase bf16 split: hh + lh + hl),
// first fout cols -> Aout (+bias), last fout -> Tout.
// 128x128 tile, 4 waves of 4x4 16x16x32 MFMA, LDS rows padded to 40 bf16.
__global__ __launch_bounds__(256) void gemm2_mfma_kernel(
        const unsigned short* __restrict__ XSh, const unsigned short* __restrict__ XSl,
        const unsigned short* __restrict__ WT, const float* __restrict__ bias,
        float* __restrict__ Aout, float* __restrict__ Tout, int fin, int fout) {
    int m0 = blockIdx.x * 128;
    int n0 = blockIdx.y * 128;
    __shared__ __align__(16) unsigned short As[128 * 40];
    __shared__ __align__(16) unsigned short Bs[128 * 40];
    int tid = threadIdx.x;
    int lane = tid & 63;
    int wave = tid >> 6;
    int wr = (wave >> 1) * 64, wc = (wave & 1) * 64;
    int l15 = lane & 15, kq = lane >> 4;
    int w2f = 2 * fin;

    f32x4 acc[4][4];
#pragma unroll
    for (int mt = 0; mt < 4; ++mt)
#pragma unroll
        for (int nt = 0; nt < 4; ++nt) acc[mt][nt] = (f32x4){0.f, 0.f, 0.f, 0.f};

    for (int p = 0; p < 3; ++p) {
        const unsigned short* Axp = (p == 1) ? XSl : XSh;
        int bkoff = (p == 2) ? fin : 0;
        for (int kc = 0; kc < fin; kc += 32) {
            __syncthreads();
            for (int i = tid; i < 512; i += 256) {
                int row = i >> 2, sub = i & 3;
                *(uint4*)&As[row * 40 + sub * 8] =
                    *(const uint4*)&Axp[(size_t)(m0 + row) * fin + kc + sub * 8];
                *(uint4*)&Bs[row * 40 + sub * 8] =
                    *(const uint4*)&WT[(size_t)(n0 + row) * w2f + bkoff + kc + sub * 8];
            }
            __syncthreads();
            bf16x8 a[4], b[4];
#pragma unroll
            for (int t = 0; t < 4; ++t) {
                a[t] = *(const bf16x8*)&As[(wr + t * 16 + l15) * 40 + kq * 8];
                b[t] = *(const bf16x8*)&Bs[(wc + t * 16 + l15) * 40 + kq * 8];
            }
#pragma unroll
            for (int mt = 0; mt < 4; ++mt)
#pragma unroll
                for (int nt = 0; nt < 4; ++nt)
                    acc[mt][nt] = __builtin_amdgcn_mfma_f32_16x16x32_bf16(a[mt], b[nt], acc[mt][nt], 0, 0, 0);
        }
    }
    // epilogue: C/D layout col=lane&15, row=(lane>>4)*4+reg  [measured m89/m91]
#pragma unroll
    for (int mt = 0; mt < 4; ++mt) {
        int mbase = m0 + wr + mt * 16 + kq * 4;
#pragma unroll
        for (int nt = 0; nt < 4; ++nt) {
            int oc = n0 + wc + nt * 16 + l15;
            f32x4 c = acc[mt][nt];
            if (oc < fout) {
                float bv = bias[oc];
#pragma unroll
                for (int r = 0; r < 4; ++r)
                    Aout[(size_t)(mbase + r) * fout + oc] = c[r] + bv;
            } else {
                int o2 = oc - fout;
#pragma unroll
                for (int r = 0; r < 4; ++r)
                    Tout[(size_t)(mbase + r) * fout + o2] = c[r];
            }
        }
    }
}

// ---------------------------------------------------------------------------
// fp32 gemm2 (kept for layer 0, fin=3)
__global__ __launch_bounds__(256) void gemm2_kernel(const float* __restrict__ x,
                                                    const float* __restrict__ w,
                                                    const float* __restrict__ bias,
                                                    float* __restrict__ Aout,
                                                    float* __restrict__ Tout,
                                                    int fin, int fout) {
    int m0 = blockIdx.x * 64;
    int o0 = blockIdx.y * 64;
    __shared__ float Xs[64][TF + 1];
    __shared__ float W1s[TF][64];
    __shared__ float W2s[TF][64];
    int tid = threadIdx.x;
    int tr = (tid / 16) * 4, tc = (tid % 16) * 4;
    float accA[4][4], accT[4][4];
#pragma unroll
    for (int i = 0; i < 4; ++i)
#pragma unroll
        for (int j = 0; j < 4; ++j) { accA[i][j] = 0.f; accT[i][j] = 0.f; }

    for (int f0 = 0; f0 < fin; f0 += TF) {
        __syncthreads();
        for (int l = tid; l < 64 * TF; l += 256) {
            int r = l / TF, f = l % TF;
            Xs[r][f] = (f0 + f < fin) ? x[(size_t)(m0 + r) * fin + f0 + f] : 0.f;
        }
        for (int l = tid; l < TF * 64; l += 256) {
            int f = l / 64, o = l % 64;
            bool ok = (f0 + f < fin);
            W1s[f][o] = ok ? w[(size_t)(f0 + f) * fout + o0 + o] : 0.f;
            W2s[f][o] = ok ? w[(size_t)(f0 + f + fin) * fout + o0 + o] : 0.f;
        }
        __syncthreads();
#pragma unroll
        for (int f = 0; f < TF; ++f) {
            float a[4], w1[4], w2[4];
#pragma unroll
            for (int i = 0; i < 4; ++i) a[i] = Xs[tr + i][f];
#pragma unroll
            for (int j = 0; j < 4; ++j) { w1[j] = W1s[f][tc + j]; w2[j] = W2s[f][tc + j]; }
#pragma unroll
            for (int i = 0; i < 4; ++i)
#pragma unroll
                for (int j = 0; j < 4; ++j) {
                    accA[i][j] += a[i] * (w1[j] - w2[j]);
                    accT[i][j] += a[i] * w2[j];
                }
        }
    }
#pragma unroll
    for (int i = 0; i < 4; ++i)
#pragma unroll
        for (int j = 0; j < 4; ++j) {
            int m = m0 + tr + i, o = o0 + tc + j;
            Aout[(size_t)m * fout + o] = accA[i][j] + bias[o];
            Tout[(size_t)m * fout + o] = accT[i][j];
        }
}

// ---------------------------------------------------------------------------
__global__ void gathermax_kernel(const float* __restrict__ A, const float* __restrict__ T,
                                 const int* __restrict__ idx, float* __restrict__ out,
                                 int fout) {
    int pn = blockIdx.x;
    int b = pn / NN;
    int o = blockIdx.y * 64 + threadIdx.x;
    const int* ip = idx + (size_t)pn * KK;
    const float* Tb = T + (size_t)b * NN * fout;
    float m = -INFINITY;
#pragma unroll
    for (int k = 0; k < KK; ++k) {
        int j = ip[k];
        m = fmaxf(m, Tb[(size_t)j * fout + o]);
    }
    float h = A[(size_t)pn * fout + o] + m;
    out[(size_t)pn * fout + o] = h > 0.f ? h : 0.2f * h;
}

// ---------------------------------------------------------------------------
__global__ void gmax_kernel(const float* __restrict__ h, float* __restrict__ g) {
    int b = blockIdx.y;
    int o = blockIdx.x * 256 + threadIdx.x;
    const float* hp = h + (size_t)b * NN * 1024 + o;
    float m = -INFINITY;
    for (int n = 0; n < NN; ++n) m = fmaxf(m, hp[(size_t)n * 1024]);
    g[(size_t)b * 1024 + o] = m;
}

// ---------------------------------------------------------------------------
__global__ __launch_bounds__(128) void mlp_kernel(const float* __restrict__ g,
                                                  const float* __restrict__ m0w, const float* __restrict__ m0b,
                                                  const float* __restrict__ m1w, const float* __restrict__ m1b,
                                                  const float* __restrict__ m2w, const float* __restrict__ m2b,
                                                  float* __restrict__ out) {
    __shared__ float gs[1024];
    __shared__ float h1[128];
    __shared__ float h2[64];
    int b = blockIdx.x, t = threadIdx.x;
    for (int i = t; i < 1024; i += 128) gs[i] = g[(size_t)b * 1024 + i];
    __syncthreads();
    float s = m0b[t];
    for (int f = 0; f < 1024; ++f) s += gs[f] * m0w[(size_t)f * 128 + t];
    h1[t] = s;
    __syncthreads();
    if (t < 64) {
        float s2 = m1b[t];
        for (int f = 0; f < 128; ++f) s2 += h1[f] * m1w[(size_t)f * 64 + t];
        h2[t] = s2;
    }
    __syncthreads();
    if (t == 0) {
        float s3 = m2b[0];
        for (int f = 0; f < 64; ++f) s3 += h2[f] * m2w[f];
        out[b] = s3;
    }
}

// ---------------------------------------------------------------------------
extern "C" void kernel_launch(void* const* d_in, const int* in_sizes, int n_in,
                              void* d_out, int out_size, void* d_ws, size_t ws_size,
                              hipStream_t stream) {
    const float* x0 = (const float*)d_in[0];
    const float* w[5], * bi[5];
    for (int i = 0; i < 5; ++i) { w[i] = (const float*)d_in[1 + 2 * i]; bi[i] = (const float*)d_in[2 + 2 * i]; }
    const float* m0w = (const float*)d_in[11]; const float* m0b = (const float*)d_in[12];
    const float* m1w = (const float*)d_in[13]; const float* m1b = (const float*)d_in[14];
    const float* m2w = (const float*)d_in[15]; const float* m2b = (const float*)d_in[16];

    float* X0 = (float*)d_ws;
    float* X1 = X0 + (size_t)BN * 1024;
    float* T  = X1 + (size_t)BN * 1024;
    float* SQ = T  + (size_t)BN * 1024;
    int*   IDX = (int*)(SQ + BN);
    float* G  = (float*)(IDX + (size_t)BN * KK);
    unsigned short* XSh = (unsigned short*)(G + (size_t)BB * 1024);
    unsigned short* XSl = XSh + (size_t)BN * 512;
    unsigned short* WT  = XSl + (size_t)BN * 512;   // max 2*1024 x 2*512 bf16 = 4MB

    // candidate buffers overlaid on T region (T written only after kNN done)
    float* candD = T;
    int*   candI = (int*)(T + (size_t)BN * SPLIT * KK);

    const int fouts[5] = {64, 128, 256, 512, 1024};
    const float* cur = x0;
    int fin = 3;
    float* bufs[2] = {X0, X1};

    for (int l = 0; l < 5; ++l) {
        int fout = fouts[l];
        float* nxt = bufs[l & 1];

        sqnorm_kernel<<<(BN + 255) / 256, 256, 0, stream>>>(cur, SQ, fin);

        dim3 kg(NN / TR, SPLIT, BB);
        knn_part_kernel<<<kg, 256, 0, stream>>>(cur, SQ, candD, candI, fin);
        knn_merge_kernel<<<(BN + 255) / 256, 256, 0, stream>>>(candD, candI, IDX);

        if (l == 0) {
            dim3 gg(BN / 64, fout / 64);
            gemm2_kernel<<<gg, 256, 0, stream>>>(cur, w[l], bi[l], nxt, T, fin, fout);
        } else {
            int nx = BN * fin;
            xsplit_kernel<<<(nx + 255) / 256, 256, 0, stream>>>(cur, XSh, XSl, nx);
            int nw = 2 * fout * fin;
            wsplit_kernel<<<(nw + 255) / 256, 256, 0, stream>>>(w[l], WT, fin, fout);
            dim3 gg(BN / 128, (2 * fout) / 128);
            gemm2_mfma_kernel<<<gg, 256, 0, stream>>>(XSh, XSl, WT, bi[l], nxt, T, fin, fout);
        }

        dim3 mg(BN, fout / 64);
        gathermax_kernel<<<mg, 64, 0, stream>>>(nxt, T, IDX, nxt, fout);

        cur = nxt;
        fin = fout;
    }

    dim3 xg(1024 / 256, BB);
    gmax_kernel<<<xg, 256, 0, stream>>>(cur, G);

    mlp_kernel<<<BB, 128, 0, stream>>>(G, m0w, m0b, m1w, m1b, m2w, m2b, (float*)d_out);
}

// Round 6
// 2368.580 us; speedup vs baseline: 5.7809x; 1.2961x over previous
//
#include <hip/hip_runtime.h>
#include <hip/hip_bf16.h>
#include <math.h>

#define BB 8
#define NN 2048
#define KK 10
#define BN (BB * NN)

#define TR 64
#define TC 64
#define TF 32
#define SPLIT 4
#define CPS (NN / SPLIT)   // 512 cols per split-block (fp32 layer-0 path)
#define NSPL 2             // col-split for MFMA knn

typedef __attribute__((ext_vector_type(8))) short bf16x8;
typedef __attribute__((ext_vector_type(4))) float f32x4;

__device__ inline unsigned short f2bf(float f) {
    unsigned int u = __float_as_uint(f);
    unsigned int r = u + 0x7fffu + ((u >> 16) & 1u);
    return (unsigned short)(r >> 16);
}
__device__ inline float bf2f(unsigned short h) {
    return __uint_as_float((unsigned int)h << 16);
}

// ---------------------------------------------------------------------------
// sq[i] = sum_f x[i,f]^2
__global__ void sqnorm_kernel(const float* __restrict__ x, float* __restrict__ sq, int F) {
    int i = blockIdx.x * blockDim.x + threadIdx.x;
    if (i >= BN) return;
    const float* xp = x + (size_t)i * F;
    float s = 0.f;
    for (int f = 0; f < F; ++f) { float v = xp[f]; s += v * v; }
    sq[i] = s;
}

// ---------------------------------------------------------------------------
// kNN fp32 path (layer 0, F=3 only) — validated round 3
__global__ __launch_bounds__(256, 4) void knn_part_kernel(const float* __restrict__ x,
                                                          const float* __restrict__ sq,
                                                          float* __restrict__ candD,
                                                          int* __restrict__ candI, int F) {
    int b = blockIdx.z;
    int row0 = blockIdx.x * TR;
    int colbase = blockIdx.y * CPS;
    const float* xb = x + (size_t)b * NN * F;
    const float* sqb = sq + (size_t)b * NN;

    __shared__ float smem[TF * 68 * 2 + TR * 65];
    float* As = smem;
    float* Bs = smem + TF * 68;
    float* Ds = smem + TF * 68 * 2;

    int tid = threadIdx.x;
    int tr = (tid / 16) * 4;
    int tc = (tid % 16) * 4;
    int srow = tid & 63;
    int squart = tid >> 6;
    int scol0 = squart * 16;

    float bestd[KK];
    int bestidx[KK];
#pragma unroll
    for (int k = 0; k < KK; ++k) { bestd[k] = INFINITY; bestidx[k] = 0x7fffffff; }

    for (int ct = 0; ct < CPS; ct += TC) {
        int col0 = colbase + ct;
        float acc[4][4];
#pragma unroll
        for (int i = 0; i < 4; ++i)
#pragma unroll
            for (int j = 0; j < 4; ++j) acc[i][j] = 0.f;

        for (int f0 = 0; f0 < F; f0 += TF) {
            __syncthreads();
            for (int l = tid; l < TR * TF; l += 256) {
                int r = l / TF, f = l % TF;
                As[f * 68 + r] = (f0 + f < F) ? xb[(size_t)(row0 + r) * F + f0 + f] : 0.f;
                Bs[f * 68 + r] = (f0 + f < F) ? xb[(size_t)(col0 + r) * F + f0 + f] : 0.f;
            }
            __syncthreads();
#pragma unroll
            for (int f = 0; f < TF; ++f) {
                float a[4], bv[4];
#pragma unroll
                for (int i = 0; i < 4; ++i) a[i] = As[f * 68 + tr + i];
#pragma unroll
                for (int j = 0; j < 4; ++j) bv[j] = Bs[f * 68 + tc + j];
#pragma unroll
                for (int i = 0; i < 4; ++i)
#pragma unroll
                    for (int j = 0; j < 4; ++j) acc[i][j] += a[i] * bv[j];
            }
        }
        __syncthreads();
#pragma unroll
        for (int i = 0; i < 4; ++i) {
            float sr = sqb[row0 + tr + i];
#pragma unroll
            for (int j = 0; j < 4; ++j) {
                Ds[(tr + i) * 65 + tc + j] = (sr + sqb[col0 + tc + j]) - 2.f * acc[i][j];
            }
        }
        __syncthreads();
#pragma unroll
        for (int cc = 0; cc < 16; ++cc) {
            int c = scol0 + cc;
            float d = Ds[srow * 65 + c];
            if (d < bestd[KK - 1]) {
                bestd[KK - 1] = d;
                bestidx[KK - 1] = col0 + c;
#pragma unroll
                for (int p = KK - 1; p > 0; --p) {
                    if (bestd[p] < bestd[p - 1]) {
                        float td = bestd[p]; bestd[p] = bestd[p - 1]; bestd[p - 1] = td;
                        int ti = bestidx[p]; bestidx[p] = bestidx[p - 1]; bestidx[p - 1] = ti;
                    }
                }
            }
        }
    }
    __syncthreads();
    float* candd_s = smem;
    int* candi_s = (int*)(smem + 256 * KK);
#pragma unroll
    for (int k = 0; k < KK; ++k) {
        candd_s[tid * KK + k] = bestd[k];
        candi_s[tid * KK + k] = bestidx[k];
    }
    __syncthreads();
    if (tid < TR) {
        int p[4] = {0, 0, 0, 0};
        size_t base = ((size_t)((size_t)b * NN + row0 + tid) * SPLIT + blockIdx.y) * KK;
        for (int s = 0; s < KK; ++s) {
            float bD = INFINITY; int bI = 0x7fffffff; int bq = 0;
#pragma unroll
            for (int q = 0; q < 4; ++q) {
                if (p[q] < KK) {
                    int li = (q * 64 + tid) * KK + p[q];
                    float d = candd_s[li]; int ii = candi_s[li];
                    if (d < bD || (d == bD && ii < bI)) { bD = d; bI = ii; bq = q; }
                }
            }
            p[bq]++;
            candD[base + s] = bD;
            candI[base + s] = bI;
        }
    }
}

// ---------------------------------------------------------------------------
// kNN MFMA path (layers 1-4): Gram via bf16 hi/lo 3-phase MFMA, d2 epilogue,
// streaming top-10. Block: 128 rows x 1024 cols (col-split 2), 8 tiles of 128.
__global__ __launch_bounds__(256, 2) void knn_mfma_kernel(
        const unsigned short* __restrict__ xh, const unsigned short* __restrict__ xl,
        const float* __restrict__ sq, float* __restrict__ candD,
        int* __restrict__ candI, int F) {
    int b = blockIdx.z;
    int row0 = blockIdx.x * 128;
    int colbase = blockIdx.y * (NN / NSPL);
    const unsigned short* xhb = xh + (size_t)b * NN * F;
    const unsigned short* xlb = xl + (size_t)b * NN * F;
    const float* sqb = sq + (size_t)b * NN;

    __shared__ __align__(16) unsigned short AsB[2 * 128 * 40];   // 20480 B
    __shared__ float DsS[64 * 133];                              // 34048 B
    unsigned short* As = AsB;
    unsigned short* Bs = AsB + 128 * 40;

    int tid = threadIdx.x;
    int lane = tid & 63;
    int wave = tid >> 6;
    int wr = (wave >> 1) * 64, wc = (wave & 1) * 64;
    int l15 = lane & 15, kq = lane >> 4;
    int whalf = wave >> 1;
    int srow = tid & 63;
    int scol0 = (tid >> 6) * 32;

    // sq for this wave's 16 output rows (fixed per block)
    float sqr[4][4];
#pragma unroll
    for (int mt = 0; mt < 4; ++mt)
#pragma unroll
        for (int r = 0; r < 4; ++r)
            sqr[mt][r] = sqb[row0 + wr + mt * 16 + kq * 4 + r];

    float bestd[2][KK];
    int besti[2][KK];
#pragma unroll
    for (int h = 0; h < 2; ++h)
#pragma unroll
        for (int k = 0; k < KK; ++k) { bestd[h][k] = INFINITY; besti[h][k] = 0x7fffffff; }

    for (int ct = 0; ct < (NN / NSPL) / 128; ++ct) {
        int col0 = colbase + ct * 128;
        f32x4 acc[4][4];
#pragma unroll
        for (int mt = 0; mt < 4; ++mt)
#pragma unroll
            for (int nt = 0; nt < 4; ++nt) acc[mt][nt] = (f32x4){0.f, 0.f, 0.f, 0.f};

        for (int p = 0; p < 3; ++p) {   // hh, lh, hl
            const unsigned short* Ap = (p == 1) ? xlb : xhb;
            const unsigned short* Bp = (p == 2) ? xlb : xhb;
            for (int kc = 0; kc < F; kc += 32) {
                __syncthreads();
                for (int i = tid; i < 512; i += 256) {
                    int row = i >> 2, sub = i & 3;
                    *(uint4*)&As[row * 40 + sub * 8] =
                        *(const uint4*)&Ap[(size_t)(row0 + row) * F + kc + sub * 8];
                    *(uint4*)&Bs[row * 40 + sub * 8] =
                        *(const uint4*)&Bp[(size_t)(col0 + row) * F + kc + sub * 8];
                }
                __syncthreads();
                bf16x8 a[4], bfr[4];
#pragma unroll
                for (int t = 0; t < 4; ++t) {
                    a[t] = *(const bf16x8*)&As[(wr + t * 16 + l15) * 40 + kq * 8];
                    bfr[t] = *(const bf16x8*)&Bs[(wc + t * 16 + l15) * 40 + kq * 8];
                }
#pragma unroll
                for (int mt = 0; mt < 4; ++mt)
#pragma unroll
                    for (int nt = 0; nt < 4; ++nt)
                        acc[mt][nt] = __builtin_amdgcn_mfma_f32_16x16x32_bf16(a[mt], bfr[nt], acc[mt][nt], 0, 0, 0);
            }
        }
        float sqc[4];
#pragma unroll
        for (int nt = 0; nt < 4; ++nt) sqc[nt] = sqb[col0 + wc + nt * 16 + l15];

        // d2 + selection in two 64-row halves (Ds = 64x133 fp32)
#pragma unroll
        for (int h = 0; h < 2; ++h) {
            __syncthreads();   // previous scan of DsS done
            if (whalf == h) {
#pragma unroll
                for (int mt = 0; mt < 4; ++mt)
#pragma unroll
                    for (int nt = 0; nt < 4; ++nt)
#pragma unroll
                        for (int r = 0; r < 4; ++r)
                            DsS[(mt * 16 + kq * 4 + r) * 133 + wc + nt * 16 + l15] =
                                (sqr[mt][r] + sqc[nt]) - 2.f * acc[mt][nt][r];
            }
            __syncthreads();
#pragma unroll
            for (int cc = 0; cc < 32; ++cc) {
                int c = scol0 + cc;
                float d = DsS[srow * 133 + c];
                if (d < bestd[h][KK - 1]) {
                    bestd[h][KK - 1] = d;
                    besti[h][KK - 1] = col0 + c;
#pragma unroll
                    for (int p = KK - 1; p > 0; --p) {
                        if (bestd[h][p] < bestd[h][p - 1]) {
                            float td = bestd[h][p]; bestd[h][p] = bestd[h][p - 1]; bestd[h][p - 1] = td;
                            int ti = besti[h][p]; besti[h][p] = besti[h][p - 1]; besti[h][p - 1] = ti;
                        }
                    }
                }
            }
        }
    }
    // in-block 4-way merge per row, per half
    float* cd = (float*)AsB;            // 2560 floats
    int* ci = (int*)AsB + 2560;         // 2560 ints (fits 20480 B)
#pragma unroll
    for (int h = 0; h < 2; ++h) {
        __syncthreads();
#pragma unroll
        for (int k = 0; k < KK; ++k) {
            cd[tid * KK + k] = bestd[h][k];
            ci[tid * KK + k] = besti[h][k];
        }
        __syncthreads();
        if (tid < 64) {
            int p[4] = {0, 0, 0, 0};
            size_t base = ((size_t)((size_t)b * NN + row0 + h * 64 + tid) * NSPL + blockIdx.y) * KK;
            for (int s = 0; s < KK; ++s) {
                float bD = INFINITY; int bI = 0x7fffffff; int bq = 0;
#pragma unroll
                for (int q = 0; q < 4; ++q) {
                    if (p[q] < KK) {
                        int li = (q * 64 + tid) * KK + p[q];
                        float d = cd[li]; int ii = ci[li];
                        if (d < bD || (d == bD && ii < bI)) { bD = d; bI = ii; bq = q; }
                    }
                }
                p[bq]++;
                candD[base + s] = bD;
                candI[base + s] = bI;
            }
        }
    }
}

// ---------------------------------------------------------------------------
// merge nsplit sorted 10-lists per row -> final top-10 indices
__global__ void knn_merge_kernel(const float* __restrict__ candD,
                                 const int* __restrict__ candI,
                                 int* __restrict__ idx, int nsplit) {
    int g = blockIdx.x * blockDim.x + threadIdx.x;
    if (g >= BN) return;
    size_t base = (size_t)g * nsplit * KK;
    int p[4] = {0, 0, 0, 0};
    int* op = idx + (size_t)g * KK;
    for (int s = 0; s < KK; ++s) {
        float bD = INFINITY; int bI = 0x7fffffff; int bq = 0;
        for (int q = 0; q < nsplit; ++q) {
            if (p[q] < KK) {
                float d = candD[base + q * KK + p[q]];
                int ii = candI[base + q * KK + p[q]];
                if (d < bD || (d == bD && ii < bI)) { bD = d; bI = ii; bq = q; }
            }
        }
        p[bq]++;
        op[s] = bI;
    }
}

// ---------------------------------------------------------------------------
// split x (fp32) into hi/lo bf16
__global__ void xsplit_kernel(const float* __restrict__ x, unsigned short* __restrict__ hi,
                              unsigned short* __restrict__ lo, int n) {
    int i = blockIdx.x * blockDim.x + threadIdx.x;
    if (i >= n) return;
    float v = x[i];
    unsigned short h = f2bf(v);
    hi[i] = h;
    lo[i] = f2bf(v - bf2f(h));
}

// ---------------------------------------------------------------------------
// Build WT[o'][2*fin] bf16: rows o'<fout -> (W1-W2) col o', else W2 col o'-fout.
__global__ void wsplit_kernel(const float* __restrict__ w, unsigned short* __restrict__ WT,
                              int fin, int fout) {
    int i = blockIdx.x * blockDim.x + threadIdx.x;
    int total = 2 * fout * fin;
    if (i >= total) return;
    int op = i % (2 * fout);
    int f = i / (2 * fout);
    float v;
    if (op < fout) v = w[(size_t)f * fout + op] - w[(size_t)(fin + f) * fout + op];
    else v = w[(size_t)(fin + f) * fout + (op - fout)];
    unsigned short h = f2bf(v);
    unsigned short l = f2bf(v - bf2f(h));
    WT[(size_t)op * (2 * fin) + f] = h;
    WT[(size_t)op * (2 * fin) + fin + f] = l;
}

// ---------------------------------------------------------------------------
// MFMA GEMM (validated round 5): A|T = xsplit @ WT^T, 3-phase bf16 split.
__global__ __launch_bounds__(256) void gemm2_mfma_kernel(
        const unsigned short* __restrict__ XSh, const unsigned short* __restrict__ XSl,
        const unsigned short* __restrict__ WT, const float* __restrict__ bias,
        float* __restrict__ Aout, float* __restrict__ Tout, int fin, int fout) {
    int m0 = blockIdx.x * 128;
    int n0 = blockIdx.y * 128;
    __shared__ __align__(16) unsigned short As[128 * 40];
    __shared__ __align__(16) unsigned short Bs[128 * 40];
    int tid = threadIdx.x;
    int lane = tid & 63;
    int wave = tid >> 6;
    int wr = (wave >> 1) * 64, wc = (wave & 1) * 64;
    int l15 = lane & 15, kq = lane >> 4;
    int w2f = 2 * fin;

    f32x4 acc[4][4];
#pragma unroll
    for (int mt = 0; mt < 4; ++mt)
#pragma unroll
        for (int nt = 0; nt < 4; ++nt) acc[mt][nt] = (f32x4){0.f, 0.f, 0.f, 0.f};

    for (int p = 0; p < 3; ++p) {
        const unsigned short* Axp = (p == 1) ? XSl : XSh;
        int bkoff = (p == 2) ? fin : 0;
        for (int kc = 0; kc < fin; kc += 32) {
            __syncthreads();
            for (int i = tid; i < 512; i += 256) {
                int row = i >> 2, sub = i & 3;
                *(uint4*)&As[row * 40 + sub * 8] =
                    *(const uint4*)&Axp[(size_t)(m0 + row) * fin + kc + sub * 8];
                *(uint4*)&Bs[row * 40 + sub * 8] =
                    *(const uint4*)&WT[(size_t)(n0 + row) * w2f + bkoff + kc + sub * 8];
            }
            __syncthreads();
            bf16x8 a[4], b[4];
#pragma unroll
            for (int t = 0; t < 4; ++t) {
                a[t] = *(const bf16x8*)&As[(wr + t * 16 + l15) * 40 + kq * 8];
                b[t] = *(const bf16x8*)&Bs[(wc + t * 16 + l15) * 40 + kq * 8];
            }
#pragma unroll
            for (int mt = 0; mt < 4; ++mt)
#pragma unroll
                for (int nt = 0; nt < 4; ++nt)
                    acc[mt][nt] = __builtin_amdgcn_mfma_f32_16x16x32_bf16(a[mt], b[nt], acc[mt][nt], 0, 0, 0);
        }
    }
#pragma unroll
    for (int mt = 0; mt < 4; ++mt) {
        int mbase = m0 + wr + mt * 16 + kq * 4;
#pragma unroll
        for (int nt = 0; nt < 4; ++nt) {
            int oc = n0 + wc + nt * 16 + l15;
            f32x4 c = acc[mt][nt];
            if (oc < fout) {
                float bv = bias[oc];
#pragma unroll
                for (int r = 0; r < 4; ++r)
                    Aout[(size_t)(mbase + r) * fout + oc] = c[r] + bv;
            } else {
                int o2 = oc - fout;
#pragma unroll
                for (int r = 0; r < 4; ++r)
                    Tout[(size_t)(mbase + r) * fout + o2] = c[r];
            }
        }
    }
}

// ---------------------------------------------------------------------------
// fp32 gemm2 (layer 0, fin=3)
__global__ __launch_bounds__(256) void gemm2_kernel(const float* __restrict__ x,
                                                    const float* __restrict__ w,
                                                    const float* __restrict__ bias,
                                                    float* __restrict__ Aout,
                                                    float* __restrict__ Tout,
                                                    int fin, int fout) {
    int m0 = blockIdx.x * 64;
    int o0 = blockIdx.y * 64;
    __shared__ float Xs[64][TF + 1];
    __shared__ float W1s[TF][64];
    __shared__ float W2s[TF][64];
    int tid = threadIdx.x;
    int tr = (tid / 16) * 4, tc = (tid % 16) * 4;
    float accA[4][4], accT[4][4];
#pragma unroll
    for (int i = 0; i < 4; ++i)
#pragma unroll
        for (int j = 0; j < 4; ++j) { accA[i][j] = 0.f; accT[i][j] = 0.f; }

    for (int f0 = 0; f0 < fin; f0 += TF) {
        __syncthreads();
        for (int l = tid; l < 64 * TF; l += 256) {
            int r = l / TF, f = l % TF;
            Xs[r][f] = (f0 + f < fin) ? x[(size_t)(m0 + r) * fin + f0 + f] : 0.f;
        }
        for (int l = tid; l < TF * 64; l += 256) {
            int f = l / 64, o = l % 64;
            bool ok = (f0 + f < fin);
            W1s[f][o] = ok ? w[(size_t)(f0 + f) * fout + o0 + o] : 0.f;
            W2s[f][o] = ok ? w[(size_t)(f0 + f + fin) * fout + o0 + o] : 0.f;
        }
        __syncthreads();
#pragma unroll
        for (int f = 0; f < TF; ++f) {
            float a[4], w1[4], w2[4];
#pragma unroll
            for (int i = 0; i < 4; ++i) a[i] = Xs[tr + i][f];
#pragma unroll
            for (int j = 0; j < 4; ++j) { w1[j] = W1s[f][tc + j]; w2[j] = W2s[f][tc + j]; }
#pragma unroll
            for (int i = 0; i < 4; ++i)
#pragma unroll
                for (int j = 0; j < 4; ++j) {
                    accA[i][j] += a[i] * (w1[j] - w2[j]);
                    accT[i][j] += a[i] * w2[j];
                }
        }
    }
#pragma unroll
    for (int i = 0; i < 4; ++i)
#pragma unroll
        for (int j = 0; j < 4; ++j) {
            int m = m0 + tr + i, o = o0 + tc + j;
            Aout[(size_t)m * fout + o] = accA[i][j] + bias[o];
            Tout[(size_t)m * fout + o] = accT[i][j];
        }
}

// ---------------------------------------------------------------------------
__global__ void gathermax_kernel(const float* __restrict__ A, const float* __restrict__ T,
                                 const int* __restrict__ idx, float* __restrict__ out,
                                 int fout) {
    int pn = blockIdx.x;
    int b = pn / NN;
    int o = blockIdx.y * 64 + threadIdx.x;
    const int* ip = idx + (size_t)pn * KK;
    const float* Tb = T + (size_t)b * NN * fout;
    float m = -INFINITY;
#pragma unroll
    for (int k = 0; k < KK; ++k) {
        int j = ip[k];
        m = fmaxf(m, Tb[(size_t)j * fout + o]);
    }
    float h = A[(size_t)pn * fout + o] + m;
    out[(size_t)pn * fout + o] = h > 0.f ? h : 0.2f * h;
}

// ---------------------------------------------------------------------------
__global__ void gmax_kernel(const float* __restrict__ h, float* __restrict__ g) {
    int b = blockIdx.y;
    int o = blockIdx.x * 256 + threadIdx.x;
    const float* hp = h + (size_t)b * NN * 1024 + o;
    float m = -INFINITY;
    for (int n = 0; n < NN; ++n) m = fmaxf(m, hp[(size_t)n * 1024]);
    g[(size_t)b * 1024 + o] = m;
}

// ---------------------------------------------------------------------------
__global__ __launch_bounds__(128) void mlp_kernel(const float* __restrict__ g,
                                                  const float* __restrict__ m0w, const float* __restrict__ m0b,
                                                  const float* __restrict__ m1w, const float* __restrict__ m1b,
                                                  const float* __restrict__ m2w, const float* __restrict__ m2b,
                                                  float* __restrict__ out) {
    __shared__ float gs[1024];
    __shared__ float h1[128];
    __shared__ float h2[64];
    int b = blockIdx.x, t = threadIdx.x;
    for (int i = t; i < 1024; i += 128) gs[i] = g[(size_t)b * 1024 + i];
    __syncthreads();
    float s = m0b[t];
    for (int f = 0; f < 1024; ++f) s += gs[f] * m0w[(size_t)f * 128 + t];
    h1[t] = s;
    __syncthreads();
    if (t < 64) {
        float s2 = m1b[t];
        for (int f = 0; f < 128; ++f) s2 += h1[f] * m1w[(size_t)f * 64 + t];
        h2[t] = s2;
    }
    __syncthreads();
    if (t == 0) {
        float s3 = m2b[0];
        for (int f = 0; f < 64; ++f) s3 += h2[f] * m2w[f];
        out[b] = s3;
    }
}

// ---------------------------------------------------------------------------
extern "C" void kernel_launch(void* const* d_in, const int* in_sizes, int n_in,
                              void* d_out, int out_size, void* d_ws, size_t ws_size,
                              hipStream_t stream) {
    const float* x0 = (const float*)d_in[0];
    const float* w[5], * bi[5];
    for (int i = 0; i < 5; ++i) { w[i] = (const float*)d_in[1 + 2 * i]; bi[i] = (const float*)d_in[2 + 2 * i]; }
    const float* m0w = (const float*)d_in[11]; const float* m0b = (const float*)d_in[12];
    const float* m1w = (const float*)d_in[13]; const float* m1b = (const float*)d_in[14];
    const float* m2w = (const float*)d_in[15]; const float* m2b = (const float*)d_in[16];

    float* X0 = (float*)d_ws;
    float* X1 = X0 + (size_t)BN * 1024;
    float* T  = X1 + (size_t)BN * 1024;
    float* SQ = T  + (size_t)BN * 1024;
    int*   IDX = (int*)(SQ + BN);
    float* G  = (float*)(IDX + (size_t)BN * KK);
    unsigned short* XSh = (unsigned short*)(G + (size_t)BB * 1024);
    unsigned short* XSl = XSh + (size_t)BN * 512;   // max fin = 512
    unsigned short* WT  = XSl + (size_t)BN * 512;   // max 2*1024 x 2*512 bf16

    // candidate buffers overlaid on T region (T written only after kNN done)
    float* candD = T;
    int*   candI = (int*)(T + (size_t)BN * 4 * KK);

    const int fouts[5] = {64, 128, 256, 512, 1024};
    const float* cur = x0;
    int fin = 3;
    float* bufs[2] = {X0, X1};

    for (int l = 0; l < 5; ++l) {
        int fout = fouts[l];
        float* nxt = bufs[l & 1];

        sqnorm_kernel<<<(BN + 255) / 256, 256, 0, stream>>>(cur, SQ, fin);

        if (l == 0) {
            dim3 kg(NN / TR, SPLIT, BB);
            knn_part_kernel<<<kg, 256, 0, stream>>>(cur, SQ, candD, candI, fin);
            knn_merge_kernel<<<(BN + 255) / 256, 256, 0, stream>>>(candD, candI, IDX, SPLIT);

            dim3 gg(BN / 64, fout / 64);
            gemm2_kernel<<<gg, 256, 0, stream>>>(cur, w[l], bi[l], nxt, T, fin, fout);
        } else {
            int nx = BN * fin;
            xsplit_kernel<<<(nx + 255) / 256, 256, 0, stream>>>(cur, XSh, XSl, nx);

            dim3 kg(NN / 128, NSPL, BB);
            knn_mfma_kernel<<<kg, 256, 0, stream>>>(XSh, XSl, SQ, candD, candI, fin);
            knn_merge_kernel<<<(BN + 255) / 256, 256, 0, stream>>>(candD, candI, IDX, NSPL);

            int nw = 2 * fout * fin;
            wsplit_kernel<<<(nw + 255) / 256, 256, 0, stream>>>(w[l], WT, fin, fout);
            dim3 gg(BN / 128, (2 * fout) / 128);
            gemm2_mfma_kernel<<<gg, 256, 0, stream>>>(XSh, XSl, WT, bi[l], nxt, T, fin, fout);
        }

        dim3 mg(BN, fout / 64);
        gathermax_kernel<<<mg, 64, 0, stream>>>(nxt, T, IDX, nxt, fout);

        cur = nxt;
        fin = fout;
    }

    dim3 xg(1024 / 256, BB);
    gmax_kernel<<<xg, 256, 0, stream>>>(cur, G);

    mlp_kernel<<<BB, 128, 0, stream>>>(G, m0w, m0b, m1w, m1b, m2w, m2b, (float*)d_out);
}

// Round 8
// 2295.123 us; speedup vs baseline: 5.9659x; 1.0320x over previous
//
#include <hip/hip_runtime.h>
#include <hip/hip_bf16.h>
#include <math.h>

#define BB 8
#define NN 2048
#define KK 10
#define BN (BB * NN)

#define TR 64
#define TC 64
#define TF 32
#define SPLIT 4
#define CPS (NN / SPLIT)   // 512 cols per split-block (fp32 layer-0 path)
#define NSPL 4             // col-split for MFMA knn

typedef __attribute__((ext_vector_type(8))) short bf16x8;
typedef __attribute__((ext_vector_type(4))) float f32x4;

__device__ inline unsigned short f2bf(float f) {
    unsigned int u = __float_as_uint(f);
    unsigned int r = u + 0x7fffu + ((u >> 16) & 1u);
    return (unsigned short)(r >> 16);
}
__device__ inline float bf2f(unsigned short h) {
    return __uint_as_float((unsigned int)h << 16);
}

// ---------------------------------------------------------------------------
// sq[i] = sum_f x[i,f]^2
__global__ void sqnorm_kernel(const float* __restrict__ x, float* __restrict__ sq, int F) {
    int i = blockIdx.x * blockDim.x + threadIdx.x;
    if (i >= BN) return;
    const float* xp = x + (size_t)i * F;
    float s = 0.f;
    for (int f = 0; f < F; ++f) { float v = xp[f]; s += v * v; }
    sq[i] = s;
}

// ---------------------------------------------------------------------------
// kNN fp32 path (layer 0, F=3 only) — validated round 3
__global__ __launch_bounds__(256, 4) void knn_part_kernel(const float* __restrict__ x,
                                                          const float* __restrict__ sq,
                                                          float* __restrict__ candD,
                                                          int* __restrict__ candI, int F) {
    int b = blockIdx.z;
    int row0 = blockIdx.x * TR;
    int colbase = blockIdx.y * CPS;
    const float* xb = x + (size_t)b * NN * F;
    const float* sqb = sq + (size_t)b * NN;

    __shared__ float smem[TF * 68 * 2 + TR * 65];
    float* As = smem;
    float* Bs = smem + TF * 68;
    float* Ds = smem + TF * 68 * 2;

    int tid = threadIdx.x;
    int tr = (tid / 16) * 4;
    int tc = (tid % 16) * 4;
    int srow = tid & 63;
    int squart = tid >> 6;
    int scol0 = squart * 16;

    float bestd[KK];
    int bestidx[KK];
#pragma unroll
    for (int k = 0; k < KK; ++k) { bestd[k] = INFINITY; bestidx[k] = 0x7fffffff; }

    for (int ct = 0; ct < CPS; ct += TC) {
        int col0 = colbase + ct;
        float acc[4][4];
#pragma unroll
        for (int i = 0; i < 4; ++i)
#pragma unroll
            for (int j = 0; j < 4; ++j) acc[i][j] = 0.f;

        for (int f0 = 0; f0 < F; f0 += TF) {
            __syncthreads();
            for (int l = tid; l < TR * TF; l += 256) {
                int r = l / TF, f = l % TF;
                As[f * 68 + r] = (f0 + f < F) ? xb[(size_t)(row0 + r) * F + f0 + f] : 0.f;
                Bs[f * 68 + r] = (f0 + f < F) ? xb[(size_t)(col0 + r) * F + f0 + f] : 0.f;
            }
            __syncthreads();
#pragma unroll
            for (int f = 0; f < TF; ++f) {
                float a[4], bv[4];
#pragma unroll
                for (int i = 0; i < 4; ++i) a[i] = As[f * 68 + tr + i];
#pragma unroll
                for (int j = 0; j < 4; ++j) bv[j] = Bs[f * 68 + tc + j];
#pragma unroll
                for (int i = 0; i < 4; ++i)
#pragma unroll
                    for (int j = 0; j < 4; ++j) acc[i][j] += a[i] * bv[j];
            }
        }
        __syncthreads();
#pragma unroll
        for (int i = 0; i < 4; ++i) {
            float sr = sqb[row0 + tr + i];
#pragma unroll
            for (int j = 0; j < 4; ++j) {
                Ds[(tr + i) * 65 + tc + j] = (sr + sqb[col0 + tc + j]) - 2.f * acc[i][j];
            }
        }
        __syncthreads();
#pragma unroll
        for (int cc = 0; cc < 16; ++cc) {
            int c = scol0 + cc;
            float d = Ds[srow * 65 + c];
            if (d < bestd[KK - 1]) {
                bestd[KK - 1] = d;
                bestidx[KK - 1] = col0 + c;
#pragma unroll
                for (int p = KK - 1; p > 0; --p) {
                    if (bestd[p] < bestd[p - 1]) {
                        float td = bestd[p]; bestd[p] = bestd[p - 1]; bestd[p - 1] = td;
                        int ti = bestidx[p]; bestidx[p] = bestidx[p - 1]; bestidx[p - 1] = ti;
                    }
                }
            }
        }
    }
    __syncthreads();
    float* candd_s = smem;
    int* candi_s = (int*)(smem + 256 * KK);
#pragma unroll
    for (int k = 0; k < KK; ++k) {
        candd_s[tid * KK + k] = bestd[k];
        candi_s[tid * KK + k] = bestidx[k];
    }
    __syncthreads();
    if (tid < TR) {
        int p[4] = {0, 0, 0, 0};
        size_t base = ((size_t)((size_t)b * NN + row0 + tid) * SPLIT + blockIdx.y) * KK;
        for (int s = 0; s < KK; ++s) {
            float bD = INFINITY; int bI = 0x7fffffff; int bq = 0;
#pragma unroll
            for (int q = 0; q < 4; ++q) {
                if (p[q] < KK) {
                    int li = (q * 64 + tid) * KK + p[q];
                    float d = candd_s[li]; int ii = candi_s[li];
                    if (d < bD || (d == bD && ii < bI)) { bD = d; bI = ii; bq = q; }
                }
            }
            p[bq]++;
            candD[base + s] = bD;
            candI[base + s] = bI;
        }
    }
}

// ---------------------------------------------------------------------------
// kNN MFMA path (layers 1-4), restructured:
//  - Ah/Al/Bh/Bl staged together per 32-K chunk (each tile fetched once,
//    2 barriers/chunk instead of 6), 48 MFMAs per 16 ds_read_b128.
//    FIXED round 8: stage ALL 2048 uint4 (it<8, 512 per tile) — round 7
//    staged half, leaving NaN LDS -> sentinel idx 0x7fffffff -> OOB gather.
//  - Ds (64x133) and merge arrays overlaid on the 40 KB staging pool.
//  - col-split 4 -> 512 blocks (2/CU avg), __launch_bounds__(256,3).
__global__ __launch_bounds__(256, 3) void knn_mfma_kernel(
        const unsigned short* __restrict__ xh, const unsigned short* __restrict__ xl,
        const float* __restrict__ sq, float* __restrict__ candD,
        int* __restrict__ candI, int F) {
    int b = blockIdx.z;
    int row0 = blockIdx.x * 128;
    int colbase = blockIdx.y * (NN / NSPL);
    const unsigned short* xhb = xh + (size_t)b * NN * F;
    const unsigned short* xlb = xl + (size_t)b * NN * F;
    const float* sqb = sq + (size_t)b * NN;

    __shared__ __align__(16) unsigned char smem_raw[40960];   // 40 KB pool
    unsigned short* Ah = (unsigned short*)smem_raw;           // [128*40]
    unsigned short* Al = Ah + 128 * 40;
    unsigned short* Bh = Al + 128 * 40;
    unsigned short* Bl = Bh + 128 * 40;
    float* DsS = (float*)smem_raw;                            // overlay [64*133]
    float* cd = (float*)smem_raw;                             // overlay merge
    int* ci = (int*)smem_raw + 2560;

    int tid = threadIdx.x;
    int lane = tid & 63;
    int wave = tid >> 6;
    int wr = (wave >> 1) * 64, wc = (wave & 1) * 64;
    int l15 = lane & 15, kq = lane >> 4;
    int whalf = wave >> 1;
    int srow = tid & 63;
    int scol0 = (tid >> 6) * 32;

    float sqr[4][4];
#pragma unroll
    for (int mt = 0; mt < 4; ++mt)
#pragma unroll
        for (int r = 0; r < 4; ++r)
            sqr[mt][r] = sqb[row0 + wr + mt * 16 + kq * 4 + r];

    float bestd[2][KK];
    int besti[2][KK];
#pragma unroll
    for (int h = 0; h < 2; ++h)
#pragma unroll
        for (int k = 0; k < KK; ++k) { bestd[h][k] = INFINITY; besti[h][k] = 0x7fffffff; }

    for (int ct = 0; ct < (NN / NSPL) / 128; ++ct) {
        int col0 = colbase + ct * 128;
        f32x4 acc[4][4];
#pragma unroll
        for (int mt = 0; mt < 4; ++mt)
#pragma unroll
            for (int nt = 0; nt < 4; ++nt) acc[mt][nt] = (f32x4){0.f, 0.f, 0.f, 0.f};

        for (int kc = 0; kc < F; kc += 32) {
            __syncthreads();   // prior frag reads / prior Ds scan done (overlay)
            // stage Ah,Al,Bh,Bl: 2048 uint4 total (512 per tile), 8 per thread
#pragma unroll
            for (int it = 0; it < 8; ++it) {
                int i = tid + it * 256;        // 0..2047
                int tile = i >> 9;             // 512 uint4 per tile
                int rs = i & 511;
                int row = rs >> 2, sub = rs & 3;   // 128 rows x 4 subs (32 shorts)
                const unsigned short* src;
                unsigned short* dst;
                if (tile == 0)      { src = xhb + (size_t)(row0 + row) * F; dst = Ah; }
                else if (tile == 1) { src = xlb + (size_t)(row0 + row) * F; dst = Al; }
                else if (tile == 2) { src = xhb + (size_t)(col0 + row) * F; dst = Bh; }
                else                { src = xlb + (size_t)(col0 + row) * F; dst = Bl; }
                *(uint4*)&dst[row * 40 + sub * 8] = *(const uint4*)&src[kc + sub * 8];
            }
            __syncthreads();
            bf16x8 bh[4], bl[4];
#pragma unroll
            for (int t = 0; t < 4; ++t) {
                bh[t] = *(const bf16x8*)&Bh[(wc + t * 16 + l15) * 40 + kq * 8];
                bl[t] = *(const bf16x8*)&Bl[(wc + t * 16 + l15) * 40 + kq * 8];
            }
#pragma unroll
            for (int mt = 0; mt < 4; ++mt) {
                bf16x8 ah = *(const bf16x8*)&Ah[(wr + mt * 16 + l15) * 40 + kq * 8];
                bf16x8 al = *(const bf16x8*)&Al[(wr + mt * 16 + l15) * 40 + kq * 8];
#pragma unroll
                for (int nt = 0; nt < 4; ++nt) {
                    acc[mt][nt] = __builtin_amdgcn_mfma_f32_16x16x32_bf16(ah, bh[nt], acc[mt][nt], 0, 0, 0);
                    acc[mt][nt] = __builtin_amdgcn_mfma_f32_16x16x32_bf16(al, bh[nt], acc[mt][nt], 0, 0, 0);
                    acc[mt][nt] = __builtin_amdgcn_mfma_f32_16x16x32_bf16(ah, bl[nt], acc[mt][nt], 0, 0, 0);
                }
            }
        }
        float sqc[4];
#pragma unroll
        for (int nt = 0; nt < 4; ++nt) sqc[nt] = sqb[col0 + wc + nt * 16 + l15];

        __syncthreads();   // all frag reads done before Ds overlay write
#pragma unroll
        for (int h = 0; h < 2; ++h) {
            if (whalf == h) {
#pragma unroll
                for (int mt = 0; mt < 4; ++mt)
#pragma unroll
                    for (int nt = 0; nt < 4; ++nt)
#pragma unroll
                        for (int r = 0; r < 4; ++r)
                            DsS[(mt * 16 + kq * 4 + r) * 133 + wc + nt * 16 + l15] =
                                (sqr[mt][r] + sqc[nt]) - 2.f * acc[mt][nt][r];
            }
            __syncthreads();
#pragma unroll
            for (int cc = 0; cc < 32; ++cc) {
                int c = scol0 + cc;
                float d = DsS[srow * 133 + c];
                if (d < bestd[h][KK - 1]) {
                    bestd[h][KK - 1] = d;
                    besti[h][KK - 1] = col0 + c;
#pragma unroll
                    for (int p = KK - 1; p > 0; --p) {
                        if (bestd[h][p] < bestd[h][p - 1]) {
                            float td = bestd[h][p]; bestd[h][p] = bestd[h][p - 1]; bestd[h][p - 1] = td;
                            int ti = besti[h][p]; besti[h][p] = besti[h][p - 1]; besti[h][p - 1] = ti;
                        }
                    }
                }
            }
            __syncthreads();   // scan done before next half's write / next stage
        }
    }
    // in-block 4-way merge per row, per half
#pragma unroll
    for (int h = 0; h < 2; ++h) {
        __syncthreads();
#pragma unroll
        for (int k = 0; k < KK; ++k) {
            cd[tid * KK + k] = bestd[h][k];
            ci[tid * KK + k] = besti[h][k];
        }
        __syncthreads();
        if (tid < 64) {
            int p[4] = {0, 0, 0, 0};
            size_t base = ((size_t)((size_t)b * NN + row0 + h * 64 + tid) * NSPL + blockIdx.y) * KK;
            for (int s = 0; s < KK; ++s) {
                float bD = INFINITY; int bI = 0x7fffffff; int bq = 0;
#pragma unroll
                for (int q = 0; q < 4; ++q) {
                    if (p[q] < KK) {
                        int li = (q * 64 + tid) * KK + p[q];
                        float d = cd[li]; int ii = ci[li];
                        if (d < bD || (d == bD && ii < bI)) { bD = d; bI = ii; bq = q; }
                    }
                }
                p[bq]++;
                candD[base + s] = bD;
                candI[base + s] = bI;
            }
        }
    }
}

// ---------------------------------------------------------------------------
// merge nsplit sorted 10-lists per row -> final top-10 indices
__global__ void knn_merge_kernel(const float* __restrict__ candD,
                                 const int* __restrict__ candI,
                                 int* __restrict__ idx, int nsplit) {
    int g = blockIdx.x * blockDim.x + threadIdx.x;
    if (g >= BN) return;
    size_t base = (size_t)g * nsplit * KK;
    int p[4] = {0, 0, 0, 0};
    int* op = idx + (size_t)g * KK;
    for (int s = 0; s < KK; ++s) {
        float bD = INFINITY; int bI = 0x7fffffff; int bq = 0;
        for (int q = 0; q < nsplit; ++q) {
            if (p[q] < KK) {
                float d = candD[base + q * KK + p[q]];
                int ii = candI[base + q * KK + p[q]];
                if (d < bD || (d == bD && ii < bI)) { bD = d; bI = ii; bq = q; }
            }
        }
        p[bq]++;
        op[s] = bI;
    }
}

// ---------------------------------------------------------------------------
// split x (fp32) into hi/lo bf16
__global__ void xsplit_kernel(const float* __restrict__ x, unsigned short* __restrict__ hi,
                              unsigned short* __restrict__ lo, int n) {
    int i = blockIdx.x * blockDim.x + threadIdx.x;
    if (i >= n) return;
    float v = x[i];
    unsigned short h = f2bf(v);
    hi[i] = h;
    lo[i] = f2bf(v - bf2f(h));
}

// ---------------------------------------------------------------------------
// Build WT[o'][2*fin] bf16: rows o'<fout -> (W1-W2) col o', else W2 col o'-fout.
__global__ void wsplit_kernel(const float* __restrict__ w, unsigned short* __restrict__ WT,
                              int fin, int fout) {
    int i = blockIdx.x * blockDim.x + threadIdx.x;
    int total = 2 * fout * fin;
    if (i >= total) return;
    int op = i % (2 * fout);
    int f = i / (2 * fout);
    float v;
    if (op < fout) v = w[(size_t)f * fout + op] - w[(size_t)(fin + f) * fout + op];
    else v = w[(size_t)(fin + f) * fout + (op - fout)];
    unsigned short h = f2bf(v);
    unsigned short l = f2bf(v - bf2f(h));
    WT[(size_t)op * (2 * fin) + f] = h;
    WT[(size_t)op * (2 * fin) + fin + f] = l;
}

// ---------------------------------------------------------------------------
// MFMA GEMM (validated round 5): A|T = xsplit @ WT^T, 3-phase bf16 split.
__global__ __launch_bounds__(256) void gemm2_mfma_kernel(
        const unsigned short* __restrict__ XSh, const unsigned short* __restrict__ XSl,
        const unsigned short* __restrict__ WT, const float* __restrict__ bias,
        float* __restrict__ Aout, float* __restrict__ Tout, int fin, int fout) {
    int m0 = blockIdx.x * 128;
    int n0 = blockIdx.y * 128;
    __shared__ __align__(16) unsigned short As[128 * 40];
    __shared__ __align__(16) unsigned short Bs[128 * 40];
    int tid = threadIdx.x;
    int lane = tid & 63;
    int wave = tid >> 6;
    int wr = (wave >> 1) * 64, wc = (wave & 1) * 64;
    int l15 = lane & 15, kq = lane >> 4;
    int w2f = 2 * fin;

    f32x4 acc[4][4];
#pragma unroll
    for (int mt = 0; mt < 4; ++mt)
#pragma unroll
        for (int nt = 0; nt < 4; ++nt) acc[mt][nt] = (f32x4){0.f, 0.f, 0.f, 0.f};

    for (int p = 0; p < 3; ++p) {
        const unsigned short* Axp = (p == 1) ? XSl : XSh;
        int bkoff = (p == 2) ? fin : 0;
        for (int kc = 0; kc < fin; kc += 32) {
            __syncthreads();
            for (int i = tid; i < 512; i += 256) {
                int row = i >> 2, sub = i & 3;
                *(uint4*)&As[row * 40 + sub * 8] =
                    *(const uint4*)&Axp[(size_t)(m0 + row) * fin + kc + sub * 8];
                *(uint4*)&Bs[row * 40 + sub * 8] =
                    *(const uint4*)&WT[(size_t)(n0 + row) * w2f + bkoff + kc + sub * 8];
            }
            __syncthreads();
            bf16x8 a[4], b[4];
#pragma unroll
            for (int t = 0; t < 4; ++t) {
                a[t] = *(const bf16x8*)&As[(wr + t * 16 + l15) * 40 + kq * 8];
                b[t] = *(const bf16x8*)&Bs[(wc + t * 16 + l15) * 40 + kq * 8];
            }
#pragma unroll
            for (int mt = 0; mt < 4; ++mt)
#pragma unroll
                for (int nt = 0; nt < 4; ++nt)
                    acc[mt][nt] = __builtin_amdgcn_mfma_f32_16x16x32_bf16(a[mt], b[nt], acc[mt][nt], 0, 0, 0);
        }
    }
#pragma unroll
    for (int mt = 0; mt < 4; ++mt) {
        int mbase = m0 + wr + mt * 16 + kq * 4;
#pragma unroll
        for (int nt = 0; nt < 4; ++nt) {
            int oc = n0 + wc + nt * 16 + l15;
            f32x4 c = acc[mt][nt];
            if (oc < fout) {
                float bv = bias[oc];
#pragma unroll
                for (int r = 0; r < 4; ++r)
                    Aout[(size_t)(mbase + r) * fout + oc] = c[r] + bv;
            } else {
                int o2 = oc - fout;
#pragma unroll
                for (int r = 0; r < 4; ++r)
                    Tout[(size_t)(mbase + r) * fout + o2] = c[r];
            }
        }
    }
}

// ---------------------------------------------------------------------------
// fp32 gemm2 (layer 0, fin=3)
__global__ __launch_bounds__(256) void gemm2_kernel(const float* __restrict__ x,
                                                    const float* __restrict__ w,
                                                    const float* __restrict__ bias,
                                                    float* __restrict__ Aout,
                                                    float* __restrict__ Tout,
                                                    int fin, int fout) {
    int m0 = blockIdx.x * 64;
    int o0 = blockIdx.y * 64;
    __shared__ float Xs[64][TF + 1];
    __shared__ float W1s[TF][64];
    __shared__ float W2s[TF][64];
    int tid = threadIdx.x;
    int tr = (tid / 16) * 4, tc = (tid % 16) * 4;
    float accA[4][4], accT[4][4];
#pragma unroll
    for (int i = 0; i < 4; ++i)
#pragma unroll
        for (int j = 0; j < 4; ++j) { accA[i][j] = 0.f; accT[i][j] = 0.f; }

    for (int f0 = 0; f0 < fin; f0 += TF) {
        __syncthreads();
        for (int l = tid; l < 64 * TF; l += 256) {
            int r = l / TF, f = l % TF;
            Xs[r][f] = (f0 + f < fin) ? x[(size_t)(m0 + r) * fin + f0 + f] : 0.f;
        }
        for (int l = tid; l < TF * 64; l += 256) {
            int f = l / 64, o = l % 64;
            bool ok = (f0 + f < fin);
            W1s[f][o] = ok ? w[(size_t)(f0 + f) * fout + o0 + o] : 0.f;
            W2s[f][o] = ok ? w[(size_t)(f0 + f + fin) * fout + o0 + o] : 0.f;
        }
        __syncthreads();
#pragma unroll
        for (int f = 0; f < TF; ++f) {
            float a[4], w1[4], w2[4];
#pragma unroll
            for (int i = 0; i < 4; ++i) a[i] = Xs[tr + i][f];
#pragma unroll
            for (int j = 0; j < 4; ++j) { w1[j] = W1s[f][tc + j]; w2[j] = W2s[f][tc + j]; }
#pragma unroll
            for (int i = 0; i < 4; ++i)
#pragma unroll
                for (int j = 0; j < 4; ++j) {
                    accA[i][j] += a[i] * (w1[j] - w2[j]);
                    accT[i][j] += a[i] * w2[j];
                }
        }
    }
#pragma unroll
    for (int i = 0; i < 4; ++i)
#pragma unroll
        for (int j = 0; j < 4; ++j) {
            int m = m0 + tr + i, o = o0 + tc + j;
            Aout[(size_t)m * fout + o] = accA[i][j] + bias[o];
            Tout[(size_t)m * fout + o] = accT[i][j];
        }
}

// ---------------------------------------------------------------------------
__global__ void gathermax_kernel(const float* __restrict__ A, const float* __restrict__ T,
                                 const int* __restrict__ idx, float* __restrict__ out,
                                 int fout) {
    int pn = blockIdx.x;
    int b = pn / NN;
    int o = blockIdx.y * 64 + threadIdx.x;
    const int* ip = idx + (size_t)pn * KK;
    const float* Tb = T + (size_t)b * NN * fout;
    float m = -INFINITY;
#pragma unroll
    for (int k = 0; k < KK; ++k) {
        int j = ip[k];
        m = fmaxf(m, Tb[(size_t)j * fout + o]);
    }
    float h = A[(size_t)pn * fout + o] + m;
    out[(size_t)pn * fout + o] = h > 0.f ? h : 0.2f * h;
}

// ---------------------------------------------------------------------------
__global__ void gmax_kernel(const float* __restrict__ h, float* __restrict__ g) {
    int b = blockIdx.y;
    int o = blockIdx.x * 256 + threadIdx.x;
    const float* hp = h + (size_t)b * NN * 1024 + o;
    float m = -INFINITY;
    for (int n = 0; n < NN; ++n) m = fmaxf(m, hp[(size_t)n * 1024]);
    g[(size_t)b * 1024 + o] = m;
}

// ---------------------------------------------------------------------------
__global__ __launch_bounds__(128) void mlp_kernel(const float* __restrict__ g,
                                                  const float* __restrict__ m0w, const float* __restrict__ m0b,
                                                  const float* __restrict__ m1w, const float* __restrict__ m1b,
                                                  const float* __restrict__ m2w, const float* __restrict__ m2b,
                                                  float* __restrict__ out) {
    __shared__ float gs[1024];
    __shared__ float h1[128];
    __shared__ float h2[64];
    int b = blockIdx.x, t = threadIdx.x;
    for (int i = t; i < 1024; i += 128) gs[i] = g[(size_t)b * 1024 + i];
    __syncthreads();
    float s = m0b[t];
    for (int f = 0; f < 1024; ++f) s += gs[f] * m0w[(size_t)f * 128 + t];
    h1[t] = s;
    __syncthreads();
    if (t < 64) {
        float s2 = m1b[t];
        for (int f = 0; f < 128; ++f) s2 += h1[f] * m1w[(size_t)f * 64 + t];
        h2[t] = s2;
    }
    __syncthreads();
    if (t == 0) {
        float s3 = m2b[0];
        for (int f = 0; f < 64; ++f) s3 += h2[f] * m2w[f];
        out[b] = s3;
    }
}

// ---------------------------------------------------------------------------
extern "C" void kernel_launch(void* const* d_in, const int* in_sizes, int n_in,
                              void* d_out, int out_size, void* d_ws, size_t ws_size,
                              hipStream_t stream) {
    const float* x0 = (const float*)d_in[0];
    const float* w[5], * bi[5];
    for (int i = 0; i < 5; ++i) { w[i] = (const float*)d_in[1 + 2 * i]; bi[i] = (const float*)d_in[2 + 2 * i]; }
    const float* m0w = (const float*)d_in[11]; const float* m0b = (const float*)d_in[12];
    const float* m1w = (const float*)d_in[13]; const float* m1b = (const float*)d_in[14];
    const float* m2w = (const float*)d_in[15]; const float* m2b = (const float*)d_in[16];

    float* X0 = (float*)d_ws;
    float* X1 = X0 + (size_t)BN * 1024;
    float* T  = X1 + (size_t)BN * 1024;
    float* SQ = T  + (size_t)BN * 1024;
    int*   IDX = (int*)(SQ + BN);
    float* G  = (float*)(IDX + (size_t)BN * KK);
    unsigned short* XSh = (unsigned short*)(G + (size_t)BB * 1024);
    unsigned short* XSl = XSh + (size_t)BN * 512;   // max fin = 512
    unsigned short* WT  = XSl + (size_t)BN * 512;   // max 2*1024 x 2*512 bf16

    // candidate buffers overlaid on T region (T written only after kNN done)
    float* candD = T;
    int*   candI = (int*)(T + (size_t)BN * 4 * KK);

    const int fouts[5] = {64, 128, 256, 512, 1024};
    const float* cur = x0;
    int fin = 3;
    float* bufs[2] = {X0, X1};

    for (int l = 0; l < 5; ++l) {
        int fout = fouts[l];
        float* nxt = bufs[l & 1];

        sqnorm_kernel<<<(BN + 255) / 256, 256, 0, stream>>>(cur, SQ, fin);

        if (l == 0) {
            dim3 kg(NN / TR, SPLIT, BB);
            knn_part_kernel<<<kg, 256, 0, stream>>>(cur, SQ, candD, candI, fin);
            knn_merge_kernel<<<(BN + 255) / 256, 256, 0, stream>>>(candD, candI, IDX, SPLIT);

            dim3 gg(BN / 64, fout / 64);
            gemm2_kernel<<<gg, 256, 0, stream>>>(cur, w[l], bi[l], nxt, T, fin, fout);
        } else {
            int nx = BN * fin;
            xsplit_kernel<<<(nx + 255) / 256, 256, 0, stream>>>(cur, XSh, XSl, nx);

            dim3 kg(NN / 128, NSPL, BB);
            knn_mfma_kernel<<<kg, 256, 0, stream>>>(XSh, XSl, SQ, candD, candI, fin);
            knn_merge_kernel<<<(BN + 255) / 256, 256, 0, stream>>>(candD, candI, IDX, NSPL);

            int nw = 2 * fout * fin;
            wsplit_kernel<<<(nw + 255) / 256, 256, 0, stream>>>(w[l], WT, fin, fout);
            dim3 gg(BN / 128, (2 * fout) / 128);
            gemm2_mfma_kernel<<<gg, 256, 0, stream>>>(XSh, XSl, WT, bi[l], nxt, T, fin, fout);
        }

        dim3 mg(BN, fout / 64);
        gathermax_kernel<<<mg, 64, 0, stream>>>(nxt, T, IDX, nxt, fout);

        cur = nxt;
        fin = fout;
    }

    dim3 xg(1024 / 256, BB);
    gmax_kernel<<<xg, 256, 0, stream>>>(cur, G);

    mlp_kernel<<<BB, 128, 0, stream>>>(G, m0w, m0b, m1w, m1b, m2w, m2b, (float*)d_out);
}